// Round 4
// baseline (720.481 us; speedup 1.0000x reference)
//
#include <hip/hip_runtime.h>
#include <math.h>

// ---- problem constants ----
#define NPATCH 16384          // B * T / P
#define SEQ    512            // T / P
#define LOSS_OFF 16777216
#define IDX_OFF  16777217

typedef short bf8 __attribute__((ext_vector_type(8)));    // 8 bf16 (4 VGPRs)
typedef _Float16 h8 __attribute__((ext_vector_type(8)));  // 8 f16 (4 VGPRs)
typedef float f32x4 __attribute__((ext_vector_type(4)));  // MFMA acc

__device__ inline short f2bf(float x) {          // fp32 -> bf16 RNE
  unsigned u = __float_as_uint(x);
  u += 0x7fffu + ((u >> 16) & 1u);
  return (short)(u >> 16);
}
__device__ inline float bf2f(short h) {
  return __uint_as_float(((unsigned)(unsigned short)h) << 16);
}

// f16 split with 4096-scaled lo plane.  hi forced to 0 below f16-normal so MFMA
// denormal handling can't matter; then lo = v*4096 carries the value exactly.
__device__ inline void splitf16(float v, short& hi, short& lo) {
  _Float16 h = (fabsf(v) < 6.1035156e-5f) ? (_Float16)0.f : (_Float16)v;
  hi = __builtin_bit_cast(short, h);
  lo = __builtin_bit_cast(short, (_Float16)((v - (float)h) * 4096.f));
}

// encoder weight plane offsets (in halfs) inside ewh/ewl
#define EW2_OFF 0        // [t][co][ci]  4*64*32  = 8192
#define EW3_OFF 8192     // [t][co][ci]  3*64*64  = 12288
#define ERA_OFF 20480    // [rl][t][co][ci] 2*3*32*64 = 12288
#define ERB_OFF 32768    // [rl][co][ci] 2*64*32  = 4096
#define EPW_OFF 36864    // [co][ci]     32*64    = 2048
#define EWTOT   38912

// ---- pre-split + transpose encoder weights into f16 hi / scaled-lo planes ----
__global__ __launch_bounds__(256) void enc_split(
    const float* __restrict__ w2, const float* __restrict__ w3,
    const float* __restrict__ rw1, const float* __restrict__ rw2,
    const float* __restrict__ pw,
    unsigned short* __restrict__ eh, unsigned short* __restrict__ el) {
  int i = blockIdx.x * 256 + threadIdx.x;     // 0..38911 exactly
  float v;
  if (i < 8192) {                 // EW2 [t][co][ci] <- w2[co][ci][t]
    int t = i >> 11, co = (i >> 5) & 63, ci = i & 31;
    v = w2[(co * 32 + ci) * 4 + t];
  } else if (i < 20480) {         // EW3 [t][co][ci] <- w3[co][ci][t]
    int j = i - 8192;
    int t = j >> 12, co = (j >> 6) & 63, ci = j & 63;
    v = w3[(co * 64 + ci) * 3 + t];
  } else if (i < 32768) {         // ERA [rl][t][co][ci] <- rw1[rl][co][ci][t]
    int j = i - 20480;
    int rl = j / 6144; j -= rl * 6144;
    int t = j >> 11, co = (j >> 6) & 31, ci = j & 63;
    v = rw1[((rl * 32 + co) * 64 + ci) * 3 + t];
  } else if (i < 36864) {         // ERB [rl][co][ci] <- rw2
    int j = i - 32768;
    int rl = j >> 11, co = (j >> 5) & 63, ci = j & 31;
    v = rw2[(rl * 64 + co) * 32 + ci];
  } else {                        // EPW [co][ci] <- pw
    int j = i - 36864;
    int co = j >> 6, ci = j & 63;
    v = pw[co * 64 + ci];
  }
  short hh_, ll_;
  splitf16(v, hh_, ll_);
  eh[i] = (unsigned short)hh_;
  el[i] = (unsigned short)ll_;
}

// ====== encoder v8: MFMA conv stack, L2-weight-traffic-first ======
// Theory: enc6/7 identical 73us across occupancy 78%/38% and VGPR 32/60 ->
// limit is L2 weight refetch (~308KB/8-patch block = 630MB total), not
// occupancy or load convoy.  v8: 32 patches/block (512 thr, 8 waves = 4mt x
// 2nh), each wave M=32 rows (2 A-tiles) reusing every weight fragment 2x
// in-register -> per-patch weight traffic 38.5 -> 9.5 KB (156MB total).
// LDS 56KB (H2 overlays H1 after a read-complete barrier); 2 blocks/CU.
// Per-output MFMA/FMA order identical to enc7 -> z bit-identical, argmin safe.
#define H1S 320    // per-patch H1 stride in halfs (8 pos * 40)
__global__ __launch_bounds__(512, 4) void encoder8(
    const float* __restrict__ x,
    const float* __restrict__ w1, const float* __restrict__ b1,
    const float* __restrict__ b2, const float* __restrict__ b3,
    const float* __restrict__ rb1, const float* __restrict__ rb2,
    const float* __restrict__ pb,
    const unsigned short* __restrict__ ewh, const unsigned short* __restrict__ ewl,
    float* __restrict__ z) {
  __shared__ __align__(16) short arena[28672];   // 57344 B
  short* H1h = arena;                    // [32 pat][8 pos][32 ch], strides 320/40
  short* H1l = arena + 10240;
  short* H2h = arena;                    // [128 m][64 ch] stride 72 (overlays H1)
  short* H2l = arena + 9216;
  short* T1h = arena + 18432;            // [128 m][32 ch] stride 40
  short* T1l = arena + 23552;

  const int tid = threadIdx.x;
  const int wave = tid >> 6, lane = tid & 63, quad = lane >> 4, l15 = lane & 15;
  const int mt = wave >> 1, nh = wave & 1;     // m-quarter (32 rows), n-half
  const size_t pbase = (size_t)blockIdx.x * 32;
  const h8 zh8 = {0, 0, 0, 0, 0, 0, 0, 0};
  const f32x4 zf4 = {0.f, 0.f, 0.f, 0.f};

  { // ---- conv1 (VALU fp32): 1->32ch, 16->8, k4 s2 p1, relu; split into H1 ----
    const int p = tid >> 4, op = (tid >> 1) & 7, hf = tid & 1;
    const float* xp = x + (pbase + p) * 16;
    float xv[4];
#pragma unroll
    for (int kk = 0; kk < 4; ++kk) {
      int ip = 2 * op + kk - 1;
      xv[kk] = ((unsigned)ip < 16u) ? xp[ip] : 0.f;
    }
    short hs[16], ls[16];
#pragma unroll
    for (int c = 0; c < 16; ++c) {
      int co = hf * 16 + c;
      float4 wv = *reinterpret_cast<const float4*>(w1 + co * 4);
      float a = b1[co] + xv[0] * wv.x + xv[1] * wv.y + xv[2] * wv.z + xv[3] * wv.w;
      a = fmaxf(a, 0.f);
      splitf16(a, hs[c], ls[c]);
    }
    const int off = p * H1S + op * 40 + hf * 16;
#pragma unroll
    for (int q = 0; q < 2; ++q) {
      bf8 sh, sl;
#pragma unroll
      for (int e = 0; e < 8; ++e) { sh[e] = hs[q * 8 + e]; sl[e] = ls[q * 8 + e]; }
      *reinterpret_cast<bf8*>(&H1h[off + q * 8]) = sh;
      *reinterpret_cast<bf8*>(&H1l[off + q * 8]) = sl;
    }
  }
  __syncthreads();

  f32x4 h3keep[2][2];                    // fp32 residual, lane-owned [at][j]

  { // ---- conv2 (MFMA): 32->64ch, 8->4, k4 s2 p1, relu ----
    const float bs0 = b2[nh * 32 + l15], bs1 = b2[nh * 32 + 16 + l15];
    f32x4 accA[2][2] = {{zf4, zf4}, {zf4, zf4}};
    f32x4 accB[2][2] = {{zf4, zf4}, {zf4, zf4}};
#pragma unroll
    for (int t = 0; t < 4; ++t) {
      h8 bh[2], bl[2];
#pragma unroll
      for (int j = 0; j < 2; ++j) {
        const int wb = EW2_OFF + (t * 64 + (nh * 2 + j) * 16 + l15) * 32 + quad * 8;
        bh[j] = *reinterpret_cast<const h8*>(ewh + wb);
        bl[j] = *reinterpret_cast<const h8*>(ewl + wb);
      }
#pragma unroll
      for (int at = 0; at < 2; ++at) {
        const int patch = mt * 8 + at * 4 + (l15 >> 2), outp = l15 & 3;
        const int ip = 2 * outp + t - 1;
        const bool vld = (unsigned)ip < 8u;
        const int aoff = patch * H1S + (vld ? ip : 0) * 40 + quad * 8;
        h8 ah = *reinterpret_cast<const h8*>(&H1h[aoff]);
        h8 al = *reinterpret_cast<const h8*>(&H1l[aoff]);
        if (!vld) { ah = zh8; al = zh8; }
#pragma unroll
        for (int j = 0; j < 2; ++j) {
          accA[at][j] = __builtin_amdgcn_mfma_f32_16x16x32_f16(ah, bh[j], accA[at][j], 0, 0, 0);
          accB[at][j] = __builtin_amdgcn_mfma_f32_16x16x32_f16(ah, bl[j], accB[at][j], 0, 0, 0);
          accB[at][j] = __builtin_amdgcn_mfma_f32_16x16x32_f16(al, bh[j], accB[at][j], 0, 0, 0);
        }
      }
    }
    __syncthreads();   // all H1 reads complete (H2 overlays H1)
#pragma unroll
    for (int at = 0; at < 2; ++at)
#pragma unroll
      for (int j = 0; j < 2; ++j) {
        const int col = (nh * 2 + j) * 16 + l15;
        const float bs = j ? bs1 : bs0;
#pragma unroll
        for (int r = 0; r < 4; ++r) {
          float v = fmaxf(accA[at][j][r] + accB[at][j][r] * (1.f / 4096.f) + bs, 0.f);
          short vh, vl;
          splitf16(v, vh, vl);
          const int m = mt * 32 + at * 16 + quad * 4 + r;
          H2h[m * 72 + col] = vh;
          H2l[m * 72 + col] = vl;
        }
      }
  }
  __syncthreads();

  { // ---- conv3 (MFMA): 64->64ch, L4, k3 p1, no act; keep h3 in regs ----
    const float bs0 = b3[nh * 32 + l15], bs1 = b3[nh * 32 + 16 + l15];
    f32x4 accA[2][2] = {{zf4, zf4}, {zf4, zf4}};
    f32x4 accB[2][2] = {{zf4, zf4}, {zf4, zf4}};
#pragma unroll
    for (int t = 0; t < 3; ++t)
#pragma unroll
      for (int ks = 0; ks < 2; ++ks) {
        h8 bh[2], bl[2];
#pragma unroll
        for (int j = 0; j < 2; ++j) {
          const int wb = EW3_OFF + (t * 64 + (nh * 2 + j) * 16 + l15) * 64 + ks * 32 + quad * 8;
          bh[j] = *reinterpret_cast<const h8*>(ewh + wb);
          bl[j] = *reinterpret_cast<const h8*>(ewl + wb);
        }
#pragma unroll
        for (int at = 0; at < 2; ++at) {
          const int pos = l15 & 3;
          const int ip = pos + t - 1;
          const bool vld = (unsigned)ip < 4u;
          const int row = (mt * 8 + at * 4 + (l15 >> 2)) * 4 + (vld ? ip : 0);
          const int aoff = row * 72 + ks * 32 + quad * 8;
          h8 ah = *reinterpret_cast<const h8*>(&H2h[aoff]);
          h8 al = *reinterpret_cast<const h8*>(&H2l[aoff]);
          if (!vld) { ah = zh8; al = zh8; }
#pragma unroll
          for (int j = 0; j < 2; ++j) {
            accA[at][j] = __builtin_amdgcn_mfma_f32_16x16x32_f16(ah, bh[j], accA[at][j], 0, 0, 0);
            accB[at][j] = __builtin_amdgcn_mfma_f32_16x16x32_f16(ah, bl[j], accB[at][j], 0, 0, 0);
            accB[at][j] = __builtin_amdgcn_mfma_f32_16x16x32_f16(al, bh[j], accB[at][j], 0, 0, 0);
          }
        }
      }
    __syncthreads();   // all H2 reads done before in-place H3r overwrite
#pragma unroll
    for (int at = 0; at < 2; ++at)
#pragma unroll
      for (int j = 0; j < 2; ++j) {
        const int col = (nh * 2 + j) * 16 + l15;
        const float bs = j ? bs1 : bs0;
#pragma unroll
        for (int r = 0; r < 4; ++r) {
          float v = accA[at][j][r] + accB[at][j][r] * (1.f / 4096.f) + bs;
          h3keep[at][j][r] = v;
          short vh, vl;
          splitf16(fmaxf(v, 0.f), vh, vl);             // H3r = relu(h3)
          const int m = mt * 32 + at * 16 + quad * 4 + r;
          H2h[m * 72 + col] = vh;
          H2l[m * 72 + col] = vl;
        }
      }
  }
  __syncthreads();

  for (int rl = 0; rl < 2; ++rl) {
    { // ---- res stage a (MFMA): relu(h3) 64->32ch k3 p1, relu -> T1 ----
      const float bsa = rb1[rl * 32 + nh * 16 + l15];
      f32x4 accA[2] = {zf4, zf4};
      f32x4 accB[2] = {zf4, zf4};
#pragma unroll
      for (int t = 0; t < 3; ++t)
#pragma unroll
        for (int ks = 0; ks < 2; ++ks) {
          const int wb = ERA_OFF + ((rl * 3 + t) * 32 + nh * 16 + l15) * 64 + ks * 32 + quad * 8;
          h8 bh = *reinterpret_cast<const h8*>(ewh + wb);
          h8 bl = *reinterpret_cast<const h8*>(ewl + wb);
#pragma unroll
          for (int at = 0; at < 2; ++at) {
            const int pos = l15 & 3;
            const int ip = pos + t - 1;
            const bool vld = (unsigned)ip < 4u;
            const int row = (mt * 8 + at * 4 + (l15 >> 2)) * 4 + (vld ? ip : 0);
            const int aoff = row * 72 + ks * 32 + quad * 8;
            h8 ah = *reinterpret_cast<const h8*>(&H2h[aoff]);
            h8 al = *reinterpret_cast<const h8*>(&H2l[aoff]);
            if (!vld) { ah = zh8; al = zh8; }
            accA[at] = __builtin_amdgcn_mfma_f32_16x16x32_f16(ah, bh, accA[at], 0, 0, 0);
            accB[at] = __builtin_amdgcn_mfma_f32_16x16x32_f16(ah, bl, accB[at], 0, 0, 0);
            accB[at] = __builtin_amdgcn_mfma_f32_16x16x32_f16(al, bh, accB[at], 0, 0, 0);
          }
        }
      // T1 region distinct from H2 -> no read/write barrier needed here
      const int col = nh * 16 + l15;
#pragma unroll
      for (int at = 0; at < 2; ++at)
#pragma unroll
        for (int r = 0; r < 4; ++r) {
          float v = fmaxf(accA[at][r] + accB[at][r] * (1.f / 4096.f) + bsa, 0.f);
          short vh, vl;
          splitf16(v, vh, vl);
          const int m = mt * 32 + at * 16 + quad * 4 + r;
          T1h[m * 40 + col] = vh;
          T1l[m * 40 + col] = vl;
        }
      __syncthreads();
    }
    { // ---- res stage b (MFMA): relu(t1) 32->64ch 1x1; h3 += out ----
      h8 wbh[2], wbl[2];
#pragma unroll
      for (int j = 0; j < 2; ++j) {
        const int wb = ERB_OFF + (rl * 64 + (nh * 2 + j) * 16 + l15) * 32 + quad * 8;
        wbh[j] = *reinterpret_cast<const h8*>(ewh + wb);
        wbl[j] = *reinterpret_cast<const h8*>(ewl + wb);
      }
      const float bsb0 = rb2[rl * 64 + nh * 32 + l15];
      const float bsb1 = rb2[rl * 64 + nh * 32 + 16 + l15];
      f32x4 accA[2][2] = {{zf4, zf4}, {zf4, zf4}};
      f32x4 accB[2][2] = {{zf4, zf4}, {zf4, zf4}};
#pragma unroll
      for (int at = 0; at < 2; ++at) {
        const int aoff = (mt * 32 + at * 16 + l15) * 40 + quad * 8;
        h8 ah = *reinterpret_cast<const h8*>(&T1h[aoff]);
        h8 al = *reinterpret_cast<const h8*>(&T1l[aoff]);
#pragma unroll
        for (int j = 0; j < 2; ++j) {
          accA[at][j] = __builtin_amdgcn_mfma_f32_16x16x32_f16(ah, wbh[j], accA[at][j], 0, 0, 0);
          accB[at][j] = __builtin_amdgcn_mfma_f32_16x16x32_f16(ah, wbl[j], accB[at][j], 0, 0, 0);
          accB[at][j] = __builtin_amdgcn_mfma_f32_16x16x32_f16(al, wbh[j], accB[at][j], 0, 0, 0);
        }
      }
      // res-b does not read H2 (residual is in regs); prior res-a H2 reads
      // completed before the T1 barrier -> safe to write H2 now
#pragma unroll
      for (int at = 0; at < 2; ++at)
#pragma unroll
        for (int j = 0; j < 2; ++j) {
          const int col = (nh * 2 + j) * 16 + l15;
          const float bs = j ? bsb1 : bsb0;
#pragma unroll
          for (int r = 0; r < 4; ++r) {
            float v = h3keep[at][j][r] + accA[at][j][r] + accB[at][j][r] * (1.f / 4096.f) + bs;
            h3keep[at][j][r] = v;
            short vh, vl;
            splitf16(fmaxf(v, 0.f), vh, vl);
            const int m = mt * 32 + at * 16 + quad * 4 + r;
            H2h[m * 72 + col] = vh;
            H2l[m * 72 + col] = vl;
          }
        }
      __syncthreads();
    }
  }

  { // ---- pre 1x1 (MFMA): relu(h3) 64->32ch -> global z (fp32) ----
    h8 wph[2], wpl[2];
#pragma unroll
    for (int ks = 0; ks < 2; ++ks) {
      const int wb = EPW_OFF + (nh * 16 + l15) * 64 + ks * 32 + quad * 8;
      wph[ks] = *reinterpret_cast<const h8*>(ewh + wb);
      wpl[ks] = *reinterpret_cast<const h8*>(ewl + wb);
    }
    const float bs = pb[nh * 16 + l15];
#pragma unroll
    for (int at = 0; at < 2; ++at) {
      f32x4 accA = zf4, accB = zf4;
      const int arow = mt * 32 + at * 16 + l15;
#pragma unroll
      for (int ks = 0; ks < 2; ++ks) {
        const int aoff = arow * 72 + ks * 32 + quad * 8;
        h8 ah = *reinterpret_cast<const h8*>(&H2h[aoff]);
        h8 al = *reinterpret_cast<const h8*>(&H2l[aoff]);
        accA = __builtin_amdgcn_mfma_f32_16x16x32_f16(ah, wph[ks], accA, 0, 0, 0);
        accB = __builtin_amdgcn_mfma_f32_16x16x32_f16(ah, wpl[ks], accB, 0, 0, 0);
        accB = __builtin_amdgcn_mfma_f32_16x16x32_f16(al, wph[ks], accB, 0, 0, 0);
      }
      // lane owns patch pn, positions r=0..3 of channel col ->
      // z_flat[n][col*4 + r] is a contiguous float4
      const int pn = mt * 8 + at * 4 + quad;
      const int col = nh * 16 + l15;
      float4 o;
      o.x = accA[0] + accB[0] * (1.f / 4096.f) + bs;
      o.y = accA[1] + accB[1] * (1.f / 4096.f) + bs;
      o.z = accA[2] + accB[2] * (1.f / 4096.f) + bs;
      o.w = accA[3] + accB[3] * (1.f / 4096.f) + bs;
      *reinterpret_cast<float4*>(z + (pbase + pn) * 128 + col * 4) = o;
    }
  }
}

// =============== weight pre-split: fp32 -> hi/lo bf16 planes (once/launch) ===============
__global__ __launch_bounds__(256) void split_w(
    const float* __restrict__ qkv_w, const float* __restrict__ proj_w,
    const float* __restrict__ f1, const float* __restrict__ f2,
    const float* __restrict__ hw, unsigned short* __restrict__ wh,
    unsigned short* __restrict__ wl) {
  int i = blockIdx.x * 256 + threadIdx.x;
  float v;
  if (i < 196608) v = qkv_w[i];
  else if (i < 262144) v = proj_w[i - 196608];
  else if (i < 393216) v = f1[i - 262144];
  else if (i < 524288) v = f2[i - 393216];
  else v = hw[i - 524288];
  short h = f2bf(v);
  wh[i] = (unsigned short)h;
  wl[i] = (unsigned short)f2bf(v - bf2f(h));
}

// ====== VQ part 2 v2: fp32 GEMM z.cb^T + inline |c|^2 + fused argmin ======
// tile 128(M) x 128(N), 8x8 micro-tile, K=128.  fp32 for argmin exactness.
__global__ __launch_bounds__(256) void vq_argmin2(
    const float* __restrict__ A, const float* __restrict__ B,
    unsigned long long* __restrict__ keys) {
  __shared__ float Ask[32][132];
  __shared__ float Bsk[32][132];
  __shared__ float cns[128];
  const int tid = threadIdx.x;
  const int n0 = blockIdx.x * 128, m0 = blockIdx.y * 128;
  const int ty = tid >> 4, tx = tid & 15;
  const int lr = tid >> 1, lh = (tid & 1) * 16;
  float acc[8][8] = {};
  float cn_part = 0.f;
  for (int k0 = 0; k0 < 128; k0 += 32) {
    const float4* ap = reinterpret_cast<const float4*>(A + (size_t)(m0 + lr) * 128 + k0 + lh);
    const float4* bp = reinterpret_cast<const float4*>(B + (size_t)(n0 + lr) * 128 + k0 + lh);
#pragma unroll
    for (int q = 0; q < 4; ++q) {
      float4 av = ap[q];
      Ask[lh + q * 4 + 0][lr] = av.x; Ask[lh + q * 4 + 1][lr] = av.y;
      Ask[lh + q * 4 + 2][lr] = av.z; Ask[lh + q * 4 + 3][lr] = av.w;
      float4 bv = bp[q];
      Bsk[lh + q * 4 + 0][lr] = bv.x; Bsk[lh + q * 4 + 1][lr] = bv.y;
      Bsk[lh + q * 4 + 2][lr] = bv.z; Bsk[lh + q * 4 + 3][lr] = bv.w;
      cn_part += bv.x * bv.x + bv.y * bv.y + bv.z * bv.z + bv.w * bv.w;
    }
    __syncthreads();
#pragma unroll 8
    for (int kk = 0; kk < 32; ++kk) {
      float a[8], b[8];
      *reinterpret_cast<float4*>(&a[0]) = *reinterpret_cast<const float4*>(&Ask[kk][ty * 8]);
      *reinterpret_cast<float4*>(&a[4]) = *reinterpret_cast<const float4*>(&Ask[kk][ty * 8 + 4]);
      *reinterpret_cast<float4*>(&b[0]) = *reinterpret_cast<const float4*>(&Bsk[kk][tx * 4]);
      *reinterpret_cast<float4*>(&b[4]) = *reinterpret_cast<const float4*>(&Bsk[kk][64 + tx * 4]);
#pragma unroll
      for (int ii = 0; ii < 8; ++ii)
#pragma unroll
        for (int jj = 0; jj < 8; ++jj) acc[ii][jj] += a[ii] * b[jj];
    }
    __syncthreads();
  }
  cn_part += __shfl_xor(cn_part, 1);
  if ((tid & 1) == 0) cns[lr] = cn_part;
  __syncthreads();
  float cnv[8];
#pragma unroll
  for (int jj = 0; jj < 4; ++jj) {
    cnv[jj] = cns[tx * 4 + jj];
    cnv[4 + jj] = cns[64 + tx * 4 + jj];
  }
#pragma unroll
  for (int ii = 0; ii < 8; ++ii) {
    int row = m0 + ty * 8 + ii;
    unsigned long long key = ~0ull;
#pragma unroll
    for (int jj = 0; jj < 8; ++jj) {
      int j = n0 + (jj < 4 ? tx * 4 + jj : 64 + tx * 4 + (jj - 4));
      float dv = cnv[jj] - 2.f * acc[ii][jj];   // |c|^2 - 2 z.c
      unsigned u = __float_as_uint(dv);
      u = (u & 0x80000000u) ? ~u : (u | 0x80000000u);  // order-preserving
      unsigned long long k = ((unsigned long long)u << 32) | (unsigned)j;
      key = k < key ? k : key;
    }
#pragma unroll
    for (int off = 1; off < 16; off <<= 1) {
      unsigned long long o = __shfl_xor(key, off);
      key = o < key ? o : key;
    }
    if (tx == 0) atomicMin(&keys[row], key);
  }
}

// ===== VQ part 3: gather q, loss partials, hh = q + pos (fp32 + split planes) =====
__global__ __launch_bounds__(256) void vq_gather3(
    const float* __restrict__ z, const float* __restrict__ cb,
    const float* __restrict__ pos, const unsigned long long* __restrict__ keys,
    float* __restrict__ hh, unsigned short* __restrict__ hh_h,
    unsigned short* __restrict__ hh_l, float* __restrict__ lpart,
    float* __restrict__ idx_out) {
  const int blk = blockIdx.x, tid = threadIdx.x;
  __shared__ int sidx[8];
  if (tid < 8) {
    unsigned long long k = keys[blk * 8 + tid];
    int id = (int)(unsigned)(k & 0xffffffffull);
    sidx[tid] = id;
    idx_out[blk * 8 + tid] = (float)id;
  }
  __syncthreads();
  const int p = tid >> 5, d = tid & 31;
  const size_t n = (size_t)blk * 8 + p;
  const int idx = sidx[p];
  float4 q = *reinterpret_cast<const float4*>(cb + (size_t)idx * 128 + d * 4);
  float4 zv = *reinterpret_cast<const float4*>(z + n * 128 + d * 4);
  float4 pv = *reinterpret_cast<const float4*>(pos + (size_t)(n & 511) * 128 + d * 4);
  float hv[4] = {q.x + pv.x, q.y + pv.y, q.z + pv.z, q.w + pv.w};
  *reinterpret_cast<float4*>(hh + n * 128 + d * 4) = *reinterpret_cast<float4*>(hv);
  ushort4 h4, l4;
  unsigned short* hp = (unsigned short*)&h4;
  unsigned short* lp = (unsigned short*)&l4;
#pragma unroll
  for (int e = 0; e < 4; ++e) {
    short hb = f2bf(hv[e]);
    hp[e] = (unsigned short)hb;
    lp[e] = (unsigned short)f2bf(hv[e] - bf2f(hb));
  }
  *reinterpret_cast<ushort4*>(&hh_h[n * 128 + d * 4]) = h4;
  *reinterpret_cast<ushort4*>(&hh_l[n * 128 + d * 4]) = l4;
  float dx = q.x - zv.x, dy = q.y - zv.y, dz = q.z - zv.z, dw = q.w - zv.w;
  float part = dx * dx + dy * dy + dz * dz + dw * dw;
#pragma unroll
  for (int o = 1; o < 64; o <<= 1) part += __shfl_xor(part, o);
  __shared__ float lred[4];
  if ((tid & 63) == 0) lred[tid >> 6] = part;
  __syncthreads();
  if (tid == 0) lpart[blk] = lred[0] + lred[1] + lred[2] + lred[3];
}

// ====== split-bf16 MFMA GEMM (pre-split inputs): C = A[M,128]*B[N,128]^T + bias ======
// tile 128(M) x 64(N).  ACT: 0=none 1=gelu.  SPLIT: 1 -> write hi/lo planes, 0 -> fp32.
template <int ACT, int SPLIT>
__global__ __launch_bounds__(256) void mgemm2(
    const unsigned short* __restrict__ Ahg, const unsigned short* __restrict__ Alg,
    const unsigned short* __restrict__ Bhg, const unsigned short* __restrict__ Blg,
    const float* __restrict__ bias, float* __restrict__ C,
    unsigned short* __restrict__ Ch, unsigned short* __restrict__ Cl, int N) {
  __shared__ short Ah[128 * 40], Al[128 * 40], Bh[64 * 40], Bl[64 * 40];
  const int tid = threadIdx.x;
  const int n0 = blockIdx.x * 64, m0 = blockIdx.y * 128;
  const int wave = tid >> 6, lane = tid & 63, quad = lane >> 4, l15 = lane & 15;
  const f32x4 z4 = {0.f, 0.f, 0.f, 0.f};
  f32x4 acc[2][4];
#pragma unroll
  for (int i = 0; i < 2; ++i)
#pragma unroll
    for (int j = 0; j < 4; ++j) acc[i][j] = z4;

  const int ra = tid >> 1, ha = (tid & 1) * 16;         // A: 128 rows, 16 shorts each
  const int rb = tid >> 2, hb = (tid & 3) * 8;          // B: 64 rows, 8 shorts each
  for (int k0 = 0; k0 < 128; k0 += 32) {
    {
      const size_t abase = (size_t)(m0 + ra) * 128 + k0 + ha;
      *reinterpret_cast<bf8*>(&Ah[ra * 40 + ha])     = *reinterpret_cast<const bf8*>(&Ahg[abase]);
      *reinterpret_cast<bf8*>(&Ah[ra * 40 + ha + 8]) = *reinterpret_cast<const bf8*>(&Ahg[abase + 8]);
      *reinterpret_cast<bf8*>(&Al[ra * 40 + ha])     = *reinterpret_cast<const bf8*>(&Alg[abase]);
      *reinterpret_cast<bf8*>(&Al[ra * 40 + ha + 8]) = *reinterpret_cast<const bf8*>(&Alg[abase + 8]);
      const size_t bbase = (size_t)(n0 + rb) * 128 + k0 + hb;
      *reinterpret_cast<bf8*>(&Bh[rb * 40 + hb]) = *reinterpret_cast<const bf8*>(&Bhg[bbase]);
      *reinterpret_cast<bf8*>(&Bl[rb * 40 + hb]) = *reinterpret_cast<const bf8*>(&Blg[bbase]);
    }
    __syncthreads();
    bf8 af[2], afl[2], bfh[4], bfl[4];
#pragma unroll
    for (int mt = 0; mt < 2; ++mt) {
      int row = wave * 32 + mt * 16 + l15;
      af[mt]  = *reinterpret_cast<const bf8*>(&Ah[row * 40 + quad * 8]);
      afl[mt] = *reinterpret_cast<const bf8*>(&Al[row * 40 + quad * 8]);
    }
#pragma unroll
    for (int nt = 0; nt < 4; ++nt) {
      int row = nt * 16 + l15;
      bfh[nt] = *reinterpret_cast<const bf8*>(&Bh[row * 40 + quad * 8]);
      bfl[nt] = *reinterpret_cast<const bf8*>(&Bl[row * 40 + quad * 8]);
    }
#pragma unroll
    for (int nt = 0; nt < 4; ++nt)
#pragma unroll
      for (int mt = 0; mt < 2; ++mt)
        acc[mt][nt] = __builtin_amdgcn_mfma_f32_16x16x32_bf16(af[mt], bfh[nt], acc[mt][nt], 0, 0, 0);
#pragma unroll
    for (int nt = 0; nt < 4; ++nt)
#pragma unroll
      for (int mt = 0; mt < 2; ++mt)
        acc[mt][nt] = __builtin_amdgcn_mfma_f32_16x16x32_bf16(af[mt], bfl[nt], acc[mt][nt], 0, 0, 0);
#pragma unroll
    for (int nt = 0; nt < 4; ++nt)
#pragma unroll
      for (int mt = 0; mt < 2; ++mt)
        acc[mt][nt] = __builtin_amdgcn_mfma_f32_16x16x32_bf16(afl[mt], bfh[nt], acc[mt][nt], 0, 0, 0);
    __syncthreads();
  }
#pragma unroll
  for (int nt = 0; nt < 4; ++nt) {
    int col = n0 + nt * 16 + l15;
    float bv = bias[col];
#pragma unroll
    for (int mt = 0; mt < 2; ++mt) {
      int rbase = m0 + wave * 32 + mt * 16 + quad * 4;
#pragma unroll
      for (int r = 0; r < 4; ++r) {
        float v = acc[mt][nt][r] + bv;
        if (ACT == 1) v = 0.5f * v * (1.f + erff(v * 0.7071067811865476f));
        if (SPLIT) {
          short hb_ = f2bf(v);
          Ch[(size_t)(rbase + r) * N + col] = (unsigned short)hb_;
          Cl[(size_t)(rbase + r) * N + col] = (unsigned short)f2bf(v - bf2f(hb_));
        } else {
          C[(size_t)(rbase + r) * N + col] = v;
        }
      }
    }
  }
}

// == split-bf16 MFMA GEMM + residual + LN (optionally + second/final LN) ==
// out = LN(A.B^T+bias+res)*g+b; FINAL=1: y = LN2(out)*g2+b2 -> planes only.
// tile 64(M) x 128(N).  K: 128 or 256.
template <int K, int FINAL>
__global__ __launch_bounds__(256) void mgemm_ln2(
    const unsigned short* __restrict__ Ahg, const unsigned short* __restrict__ Alg,
    const unsigned short* __restrict__ Bhg, const unsigned short* __restrict__ Blg,
    const float* __restrict__ bias, const float* __restrict__ res,
    const float* __restrict__ g, const float* __restrict__ bb,
    const float* __restrict__ g2, const float* __restrict__ bb2,
    float* __restrict__ C, unsigned short* __restrict__ Ch,
    unsigned short* __restrict__ Cl) {
  __shared__ short Ah[64 * 40], Al[64 * 40], Bh[128 * 40], Bl[128 * 40];
  const int tid = threadIdx.x;
  const int m0 = blockIdx.x * 64;
  const int wave = tid >> 6, lane = tid & 63, quad = lane >> 4, l15 = lane & 15;
  const f32x4 z4 = {0.f, 0.f, 0.f, 0.f};
  f32x4 acc[8];
#pragma unroll
  for (int j = 0; j < 8; ++j) acc[j] = z4;

  const int ra = tid >> 2, ha = (tid & 3) * 8;          // A: 64 rows, 8 shorts each
  const int rb = tid >> 1, hb = (tid & 1) * 16;         // B: 128 rows, 16 shorts each
  for (int k0 = 0; k0 < K; k0 += 32) {
    {
      const size_t abase = (size_t)(m0 + ra) * K + k0 + ha;
      *reinterpret_cast<bf8*>(&Ah[ra * 40 + ha]) = *reinterpret_cast<const bf8*>(&Ahg[abase]);
      *reinterpret_cast<bf8*>(&Al[ra * 40 + ha]) = *reinterpret_cast<const bf8*>(&Alg[abase]);
      const size_t bbase = (size_t)rb * K + k0 + hb;
      *reinterpret_cast<bf8*>(&Bh[rb * 40 + hb])     = *reinterpret_cast<const bf8*>(&Bhg[bbase]);
      *reinterpret_cast<bf8*>(&Bh[rb * 40 + hb + 8]) = *reinterpret_cast<const bf8*>(&Bhg[bbase + 8]);
      *reinterpret_cast<bf8*>(&Bl[rb * 40 + hb])     = *reinterpret_cast<const bf8*>(&Blg[bbase]);
      *reinterpret_cast<bf8*>(&Bl[rb * 40 + hb + 8]) = *reinterpret_cast<const bf8*>(&Blg[bbase + 8]);
    }
    __syncthreads();
    bf8 af, afl, bfh[8], bfl[8];
    {
      int row = wave * 16 + l15;
      af  = *reinterpret_cast<const bf8*>(&Ah[row * 40 + quad * 8]);
      afl = *reinterpret_cast<const bf8*>(&Al[row * 40 + quad * 8]);
    }
#pragma unroll
    for (int nt = 0; nt < 8; ++nt) {
      int row = nt * 16 + l15;
      bfh[nt] = *reinterpret_cast<const bf8*>(&Bh[row * 40 + quad * 8]);
      bfl[nt] = *reinterpret_cast<const bf8*>(&Bl[row * 40 + quad * 8]);
    }
#pragma unroll
    for (int nt = 0; nt < 8; ++nt)
      acc[nt] = __builtin_amdgcn_mfma_f32_16x16x32_bf16(af, bfh[nt], acc[nt], 0, 0, 0);
#pragma unroll
    for (int nt = 0; nt < 8; ++nt)
      acc[nt] = __builtin_amdgcn_mfma_f32_16x16x32_bf16(af, bfl[nt], acc[nt], 0, 0, 0);
#pragma unroll
    for (int nt = 0; nt < 8; ++nt)
      acc[nt] = __builtin_amdgcn_mfma_f32_16x16x32_bf16(afl, bfh[nt], acc[nt], 0, 0, 0);
    __syncthreads();
  }
  float bias_v[8], g_v[8], bb_v[8], g2_v[8], bb2_v[8];
#pragma unroll
  for (int nt = 0; nt < 8; ++nt) {
    int col = nt * 16 + l15;
    bias_v[nt] = bias[col]; g_v[nt] = g[col]; bb_v[nt] = bb[col];
    if (FINAL) { g2_v[nt] = g2[col]; bb2_v[nt] = bb2[col]; }
  }
  const int rbase = m0 + wave * 16 + quad * 4;
#pragma unroll
  for (int r = 0; r < 4; ++r) {
    const int row = rbase + r;
    float ov[8];
    float s = 0.f;
#pragma unroll
    for (int nt = 0; nt < 8; ++nt) {
      ov[nt] = acc[nt][r] + bias_v[nt] + res[(size_t)row * 128 + nt * 16 + l15];
      s += ov[nt];
    }
    s += __shfl_xor(s, 1); s += __shfl_xor(s, 2);
    s += __shfl_xor(s, 4); s += __shfl_xor(s, 8);
    float mean = s * 0.0078125f;
    float s2 = 0.f;
#pragma unroll
    for (int nt = 0; nt < 8; ++nt) { ov[nt] -= mean; s2 += ov[nt] * ov[nt]; }
    s2 += __shfl_xor(s2, 1); s2 += __shfl_xor(s2, 2);
    s2 += __shfl_xor(s2, 4); s2 += __shfl_xor(s2, 8);
    float rstd = rsqrtf(s2 * 0.0078125f + 1e-5f);
    if (FINAL) {
      float yv[8];
      float s3 = 0.f;
#pragma unroll
      for (int nt = 0; nt < 8; ++nt) { yv[nt] = ov[nt] * rstd * g_v[nt] + bb_v[nt]; s3 += yv[nt]; }
      s3 += __shfl_xor(s3, 1); s3 += __shfl_xor(s3, 2);
      s3 += __shfl_xor(s3, 4); s3 += __shfl_xor(s3, 8);
      float mean2 = s3 * 0.0078125f;
      float s4 = 0.f;
#pragma unroll
      for (int nt = 0; nt < 8; ++nt) { yv[nt] -= mean2; s4 += yv[nt] * yv[nt]; }
      s4 += __shfl_xor(s4, 1); s4 += __shfl_xor(s4, 2);
      s4 += __shfl_xor(s4, 4); s4 += __shfl_xor(s4, 8);
      float rstd2 = rsqrtf(s4 * 0.0078125f + 1e-5f);
#pragma unroll
      for (int nt = 0; nt < 8; ++nt) {
        float v = yv[nt] * rstd2 * g2_v[nt] + bb2_v[nt];
        size_t off = (size_t)row * 128 + nt * 16 + l15;
        short hb_ = f2bf(v);
        Ch[off] = (unsigned short)hb_;
        Cl[off] = (unsigned short)f2bf(v - bf2f(hb_));
      }
    } else {
#pragma unroll
      for (int nt = 0; nt < 8; ++nt) {
        float v = ov[nt] * rstd * g_v[nt] + bb_v[nt];
        size_t off = (size_t)row * 128 + nt * 16 + l15;
        C[off] = v;
        short hb_ = f2bf(v);
        Ch[off] = (unsigned short)hb_;
        Cl[off] = (unsigned short)f2bf(v - bf2f(hb_));
      }
    }
  }
}

// ====== MFMA flash attention: block per (qt,h,b); reads/writes split planes ======
__global__ __launch_bounds__(256) void attn3(
    const unsigned short* __restrict__ qh_, const unsigned short* __restrict__ ql_,
    unsigned short* __restrict__ oh, unsigned short* __restrict__ ol) {
  const int qt = blockIdx.x, h = blockIdx.y, b = blockIdx.z;
  __shared__ short Kh[64 * 40], Kl[64 * 40];     // [key][d]
  __shared__ short Vth[32 * 72], Vtl[32 * 72];   // [d][key]
  __shared__ float Ss[64 * 72];
  __shared__ float ms[64], ls[64], alphas[64];
  const int tid = threadIdx.x;
  const int wave = tid >> 6, lane = tid & 63, quad = lane >> 4, l15 = lane & 15;
  const size_t tbase = (size_t)b * 512 + qt * 64;
  bf8 qfh, qfl;
  {
    const size_t qoff = (tbase + wave * 16 + l15) * 384 + h * 32 + quad * 8;
    qfh = *reinterpret_cast<const bf8*>(&qh_[qoff]);
    qfl = *reinterpret_cast<const bf8*>(&ql_[qoff]);
  }
  if (tid < 64) { ms[tid] = -1e30f; ls[tid] = 0.f; }
  const f32x4 z4 = {0.f, 0.f, 0.f, 0.f};
  f32x4 o[2] = {z4, z4};
  const float scale = 0.17677669529663687f;  // 1/sqrt(32)
  const int sr = tid >> 2, sc8 = (tid & 3) * 8;
  for (int kt = 0; kt <= qt; ++kt) {
    const size_t kbase = (size_t)b * 512 + kt * 64;
    {
      const size_t koff = (kbase + sr) * 384 + 128 + h * 32 + sc8;
      *reinterpret_cast<bf8*>(&Kh[sr * 40 + sc8]) = *reinterpret_cast<const bf8*>(&qh_[koff]);
      *reinterpret_cast<bf8*>(&Kl[sr * 40 + sc8]) = *reinterpret_cast<const bf8*>(&ql_[koff]);
      const size_t voff = (kbase + sr) * 384 + 256 + h * 32 + sc8;
      bf8 vh8 = *reinterpret_cast<const bf8*>(&qh_[voff]);
      bf8 vl8 = *reinterpret_cast<const bf8*>(&ql_[voff]);
#pragma unroll
      for (int j = 0; j < 8; ++j) {
        Vth[(sc8 + j) * 72 + sr] = vh8[j];
        Vtl[(sc8 + j) * 72 + sr] = vl8[j];
      }
    }
    __syncthreads();
    {
#pragma unroll
      for (int nt = 0; nt < 4; ++nt) {
        const int krow = nt * 16 + l15;
        bf8 kfh = *reinterpret_cast<const bf8*>(&Kh[krow * 40 + quad * 8]);
        bf8 kfl = *reinterpret_cast<const bf8*>(&Kl[krow * 40 + quad * 8]);
        f32x4 s = z4;
        s = __builtin_amdgcn_mfma_f32_16x16x32_bf16(qfh, kfh, s, 0, 0, 0);
        s = __builtin_amdgcn_mfma_f32_16x16x32_bf16(qfh, kfl, s, 0, 0, 0);
        s = __builtin_amdgcn_mfma_f32_16x16x32_bf16(qfl, kfh, s, 0, 0, 0);
#pragma unroll
        for (int r = 0; r < 4; ++r) {
          int row64 = wave * 16 + quad * 4 + r;
          int col64 = nt * 16 + l15;
          float v = s[r] * scale;
          if (kt == qt && col64 > row64) v += -1e9f;
          Ss[row64 * 72 + col64] = v;
        }
      }
    }
    __syncthreads();
    {
      const int i = tid >> 2, q = tid & 3;
      float mx = -3.4e38f;
      float4 pv[4];
#pragma unroll
      for (int t = 0; t < 4; ++t) {
        pv[t] = *reinterpret_cast<const float4*>(&Ss[i * 72 + q * 16 + t * 4]);
        mx = fmaxf(mx, fmaxf(fmaxf(pv[t].x, pv[t].y), fmaxf(pv[t].z, pv[t].w)));
      }
      mx = fmaxf(mx, __shfl_xor(mx, 1));
      mx = fmaxf(mx, __shfl_xor(mx, 2));
      float mold = ms[i];
      mx = fmaxf(mx, mold);
      float sum = 0.f;
#pragma unroll
      for (int t = 0; t < 4; ++t) {
        pv[t].x = __expf(pv[t].x - mx); pv[t].y = __expf(pv[t].y - mx);
        pv[t].z = __expf(pv[t].z - mx); pv[t].w = __expf(pv[t].w - mx);
        sum += pv[t].x + pv[t].y + pv[t].z + pv[t].w;
        *reinterpret_cast<float4*>(&Ss[i * 72 + q * 16 + t * 4]) = pv[t];
      }
      sum += __shfl_xor(sum, 1);
      sum += __shfl_xor(sum, 2);
      if (q == 0) {
        float alpha = __expf(mold - mx);
        ls[i] = ls[i] * alpha + sum;
        ms[i] = mx;
        alphas[i] = alpha;
      }
    }
    __syncthreads();
    {
      bf8 ph[2], pl[2];
#pragma unroll
      for (int c = 0; c < 2; ++c) {
        const float* pp = &Ss[(wave * 16 + l15) * 72 + c * 32 + quad * 8];
        float4 p0 = *reinterpret_cast<const float4*>(pp);
        float4 p1 = *reinterpret_cast<const float4*>(pp + 4);
        float pf[8] = {p0.x, p0.y, p0.z, p0.w, p1.x, p1.y, p1.z, p1.w};
#pragma unroll
        for (int j = 0; j < 8; ++j) {
          short hb_ = f2bf(pf[j]);
          ph[c][j] = hb_;
          pl[c][j] = f2bf(pf[j] - bf2f(hb_));
        }
      }
      float a0 = alphas[wave * 16 + quad * 4 + 0];
      float a1 = alphas[wave * 16 + quad * 4 + 1];
      float a2 = alphas[wave * 16 + quad * 4 + 2];
      float a3 = alphas[wave * 16 + quad * 4 + 3];
#pragma unroll
      for (int dt = 0; dt < 2; ++dt) {
        o[dt][0] *= a0; o[dt][1] *= a1; o[dt][2] *= a2; o[dt][3] *= a3;
#pragma unroll
        for (int c = 0; c < 2; ++c) {
          const int vrow = dt * 16 + l15;
          bf8 vfh = *reinterpret_cast<const bf8*>(&Vth[vrow * 72 + c * 32 + quad * 8]);
          bf8 vfl = *reinterpret_cast<const bf8*>(&Vtl[vrow * 72 + c * 32 + quad * 8]);
          o[dt] = __builtin_amdgcn_mfma_f32_16x16x32_bf16(ph[c], vfh, o[dt], 0, 0, 0);
          o[dt] = __builtin_amdgcn_mfma_f32_16x16x32_bf16(ph[c], vfl, o[dt], 0, 0, 0);
          o[dt] = __builtin_amdgcn_mfma_f32_16x16x32_bf16(pl[c], vfh, o[dt], 0, 0, 0);
        }
      }
    }
    __syncthreads();
  }
#pragma unroll
  for (int r = 0; r < 4; ++r) {
    float inv = 1.f / ls[wave * 16 + quad * 4 + r];
    size_t row = tbase + wave * 16 + quad * 4 + r;
#pragma unroll
    for (int dt = 0; dt < 2; ++dt) {
      float v = o[dt][r] * inv;
      short hb_ = f2bf(v);
      size_t off = row * 128 + h * 32 + dt * 16 + l15;
      oh[off] = (unsigned short)hb_;
      ol[off] = (unsigned short)f2bf(v - bf2f(hb_));
    }
  }
}

__global__ __launch_bounds__(256) void loss_finalize2(const float* __restrict__ lp,
                                                      float* __restrict__ out) {
  float s = 0.f;
  for (int i = threadIdx.x; i < 2048; i += 256) s += lp[i];
#pragma unroll
  for (int o = 1; o < 64; o <<= 1) s += __shfl_xor(s, o);
  __shared__ float red[4];
  if ((threadIdx.x & 63) == 0) red[threadIdx.x >> 6] = s;
  __syncthreads();
  if (threadIdx.x == 0)
    out[0] = 1.25f * (red[0] + red[1] + red[2] + red[3]) / 2097152.0f;
}

extern "C" void kernel_launch(void* const* d_in, const int* in_sizes, int n_in,
                              void* d_out, int out_size, void* d_ws, size_t ws_size,
                              hipStream_t stream) {
  const float* x      = (const float*)d_in[0];
  const float* enc_w1 = (const float*)d_in[1];
  const float* enc_b1 = (const float*)d_in[2];
  const float* enc_w2 = (const float*)d_in[3];
  const float* enc_b2 = (const float*)d_in[4];
  const float* enc_w3 = (const float*)d_in[5];
  const float* enc_b3 = (const float*)d_in[6];
  const float* res_w1 = (const float*)d_in[7];
  const float* res_b1 = (const float*)d_in[8];
  const float* res_w2 = (const float*)d_in[9];
  const float* res_b2 = (const float*)d_in[10];
  const float* pre_w  = (const float*)d_in[11];
  const float* pre_b  = (const float*)d_in[12];
  const float* codebook = (const float*)d_in[13];
  const float* pos_emb  = (const float*)d_in[14];
  const float* qkv_w  = (const float*)d_in[15];
  const float* qkv_b  = (const float*)d_in[16];
  const float* proj_w = (const float*)d_in[17];
  const float* proj_b = (const float*)d_in[18];
  const float* ln1_g  = (const float*)d_in[19];
  const float* ln1_b  = (const float*)d_in[20];
  const float* ln2_g  = (const float*)d_in[21];
  const float* ln2_b  = (const float*)d_in[22];
  const float* ffn_w1 = (const float*)d_in[23];
  const float* ffn_b1 = (const float*)d_in[24];
  const float* ffn_w2 = (const float*)d_in[25];
  const float* ffn_b2 = (const float*)d_in[26];
  const float* fin_g  = (const float*)d_in[27];
  const float* fin_b  = (const float*)d_in[28];
  const float* head_w = (const float*)d_in[29];
  const float* head_b = (const float*)d_in[30];

  float* out = (float*)d_out;
  float* ws  = (float*)d_ws;

  // ws: keys(32768f) | lpart(2048) | pad | wh/wl planes | hhln planes
  unsigned long long* keys = (unsigned long long*)ws;
  float* lpart = ws + 32768;
  unsigned short* wh = (unsigned short*)(ws + 36864);
  unsigned short* wl = (unsigned short*)(ws + 36864 + 327680);
  unsigned short* hhln_h = (unsigned short*)(ws + 692224);
  unsigned short* hhln_l = (unsigned short*)(ws + 692224 + 1048576);

  // d_out scratch overlay (float offsets; dead before head GEMM)
  float* zf = out;                                            // [0 .. 2^21)
  float* hh = out + 2097152;                                  // [2^21 .. 2^22)
  unsigned short* hh_h   = (unsigned short*)(out + 4194304);
  unsigned short* hh_l   = (unsigned short*)(out + 5242880);
  unsigned short* qkvb_h = (unsigned short*)(out + 6291456);
  unsigned short* qkvb_l = (unsigned short*)(out + 9437184);
  unsigned short* oatt_h = (unsigned short*)(out + 12582912);
  unsigned short* oatt_l = (unsigned short*)(out + 13631488);
  unsigned short* fbuf_h = (unsigned short*)(out + 0);        // overlays zf (dead)
  unsigned short* fbuf_l = (unsigned short*)(out + 14680064);

  // encoder weight planes overlay qkvb region (dead until first mgemm2)
  unsigned short* ewh = (unsigned short*)(out + 6291456);
  unsigned short* ewl = ewh + EWTOT;

  const int W_QKV = 0, W_PROJ = 196608, W_F1 = 262144, W_F2 = 393216, W_HEAD = 524288;

  hipMemsetAsync(keys, 0xFF, NPATCH * sizeof(unsigned long long), stream);

  enc_split<<<152, 256, 0, stream>>>(enc_w2, enc_w3, res_w1, res_w2, pre_w, ewh, ewl);
  encoder8<<<512, 512, 0, stream>>>(x, enc_w1, enc_b1, enc_b2, enc_b3,
                                    res_b1, res_b2, pre_b, ewh, ewl, zf);
  split_w<<<2560, 256, 0, stream>>>(qkv_w, proj_w, ffn_w1, ffn_w2, head_w, wh, wl);
  vq_argmin2<<<dim3(8, 128), 256, 0, stream>>>(zf, codebook, keys);
  vq_gather3<<<2048, 256, 0, stream>>>(zf, codebook, pos_emb, keys, hh, hh_h, hh_l,
                                       lpart, out + IDX_OFF);
  for (int i = 0; i < 4; ++i) {
    mgemm2<0, 1><<<dim3(6, 128), 256, 0, stream>>>(
        hh_h, hh_l, wh + W_QKV + i * 49152, wl + W_QKV + i * 49152,
        qkv_b + i * 384, nullptr, qkvb_h, qkvb_l, 384);
    attn3<<<dim3(8, 4, 32), 256, 0, stream>>>(qkvb_h, qkvb_l, oatt_h, oatt_l);
    mgemm_ln2<128, 0><<<256, 256, 0, stream>>>(
        oatt_h, oatt_l, wh + W_PROJ + i * 16384, wl + W_PROJ + i * 16384,
        proj_b + i * 128, hh, ln1_g + i * 128, ln1_b + i * 128,
        nullptr, nullptr, hh, hh_h, hh_l);
    mgemm2<1, 1><<<dim3(4, 128), 256, 0, stream>>>(
        hh_h, hh_l, wh + W_F1 + i * 32768, wl + W_F1 + i * 32768,
        ffn_b1 + i * 256, nullptr, fbuf_h, fbuf_l, 256);
    if (i < 3) {
      mgemm_ln2<256, 0><<<256, 256, 0, stream>>>(
          fbuf_h, fbuf_l, wh + W_F2 + i * 32768, wl + W_F2 + i * 32768,
          ffn_b2 + i * 128, hh, ln2_g + i * 128, ln2_b + i * 128,
          nullptr, nullptr, hh, hh_h, hh_l);
    } else {
      mgemm_ln2<256, 1><<<256, 256, 0, stream>>>(
          fbuf_h, fbuf_l, wh + W_F2 + i * 32768, wl + W_F2 + i * 32768,
          ffn_b2 + i * 128, hh, ln2_g + i * 128, ln2_b + i * 128,
          fin_g, fin_b, hh, hhln_h, hhln_l);
    }
  }
  mgemm2<0, 0><<<dim3(16, 128), 256, 0, stream>>>(
      hhln_h, hhln_l, wh + W_HEAD, wl + W_HEAD, head_b, out, nullptr, nullptr, 1024);
  loss_finalize2<<<1, 256, 0, stream>>>(lpart, out + LOSS_OFF);
}

// Round 6
// 668.826 us; speedup vs baseline: 1.0772x; 1.0772x over previous
//
#include <hip/hip_runtime.h>
#include <math.h>

// ---- problem constants ----
#define NPATCH 16384          // B * T / P
#define SEQ    512            // T / P
#define LOSS_OFF 16777216
#define IDX_OFF  16777217

typedef short bf8 __attribute__((ext_vector_type(8)));    // 8 bf16 (4 VGPRs)
typedef _Float16 h8 __attribute__((ext_vector_type(8)));  // 8 f16 (4 VGPRs)
typedef float f32x4 __attribute__((ext_vector_type(4)));  // MFMA acc

__device__ inline short f2bf(float x) {          // fp32 -> bf16 RNE
  unsigned u = __float_as_uint(x);
  u += 0x7fffu + ((u >> 16) & 1u);
  return (short)(u >> 16);
}
__device__ inline float bf2f(short h) {
  return __uint_as_float(((unsigned)(unsigned short)h) << 16);
}

// f16 split with 4096-scaled lo plane.  hi forced to 0 below f16-normal so MFMA
// denormal handling can't matter; then lo = v*4096 carries the value exactly.
// NOTE (R5): for VQ operands, pre-scale v by a power of two so values sit in
// f16-normal range; otherwise the clamp degrades representation to 12 bits
// (R4 failure: ~45% of z elements clamped -> argmin flip).
__device__ inline void splitf16(float v, short& hi, short& lo) {
  _Float16 h = (fabsf(v) < 6.1035156e-5f) ? (_Float16)0.f : (_Float16)v;
  hi = __builtin_bit_cast(short, h);
  lo = __builtin_bit_cast(short, (_Float16)((v - (float)h) * 4096.f));
}

// encoder weight plane offsets (in halfs) inside ewh/ewl
#define EW2_OFF 0        // [t][co][ci]  4*64*32  = 8192
#define EW3_OFF 8192     // [t][co][ci]  3*64*64  = 12288
#define ERA_OFF 20480    // [rl][t][co][ci] 2*3*32*64 = 12288
#define ERB_OFF 32768    // [rl][co][ci] 2*64*32  = 4096
#define EPW_OFF 36864    // [co][ci]     32*64    = 2048
#define EWTOT   38912

// ---- pre-split + transpose encoder weights into f16 hi / scaled-lo planes ----
__global__ __launch_bounds__(256) void enc_split(
    const float* __restrict__ w2, const float* __restrict__ w3,
    const float* __restrict__ rw1, const float* __restrict__ rw2,
    const float* __restrict__ pw,
    unsigned short* __restrict__ eh, unsigned short* __restrict__ el) {
  int i = blockIdx.x * 256 + threadIdx.x;     // 0..38911 exactly
  float v;
  if (i < 8192) {                 // EW2 [t][co][ci] <- w2[co][ci][t]
    int t = i >> 11, co = (i >> 5) & 63, ci = i & 31;
    v = w2[(co * 32 + ci) * 4 + t];
  } else if (i < 20480) {         // EW3 [t][co][ci] <- w3[co][ci][t]
    int j = i - 8192;
    int t = j >> 12, co = (j >> 6) & 63, ci = j & 63;
    v = w3[(co * 64 + ci) * 3 + t];
  } else if (i < 32768) {         // ERA [rl][t][co][ci] <- rw1[rl][co][ci][t]
    int j = i - 20480;
    int rl = j / 6144; j -= rl * 6144;
    int t = j >> 11, co = (j >> 6) & 31, ci = j & 63;
    v = rw1[((rl * 32 + co) * 64 + ci) * 3 + t];
  } else if (i < 36864) {         // ERB [rl][co][ci] <- rw2
    int j = i - 32768;
    int rl = j >> 11, co = (j >> 5) & 63, ci = j & 31;
    v = rw2[(rl * 64 + co) * 32 + ci];
  } else {                        // EPW [co][ci] <- pw
    int j = i - 36864;
    int co = j >> 6, ci = j & 63;
    v = pw[co * 64 + ci];
  }
  short hh_, ll_;
  splitf16(v, hh_, ll_);
  eh[i] = (unsigned short)hh_;
  el[i] = (unsigned short)ll_;
}

// ---- codebook split (x64 pre-scale) + fp32 |c|^2 ----
__global__ __launch_bounds__(256) void cb_split(
    const float* __restrict__ cb, unsigned short* __restrict__ ch,
    unsigned short* __restrict__ cl, float* __restrict__ cn) {
  const int i = blockIdx.x * 256 + threadIdx.x;   // 0..131071 exactly (512 blocks)
  float v = cb[i];
  short hi, lo;
  splitf16(v * 64.f, hi, lo);                     // c*64 in [-.0625,.0625]: f16-normal
  ch[i] = (unsigned short)hi;
  cl[i] = (unsigned short)lo;
  float s = v * v;                                // row = i>>7 (2 rows/block)
#pragma unroll
  for (int o = 1; o < 64; o <<= 1) s += __shfl_xor(s, o);
  __shared__ float red[4];
  if ((threadIdx.x & 63) == 0) red[threadIdx.x >> 6] = s;
  __syncthreads();
  if (threadIdx.x == 0)   cn[i >> 7] = red[0] + red[1];
  if (threadIdx.x == 128) cn[i >> 7] = red[2] + red[3];
}

// ====== encoder v7 (proven 73us config) + z hi/lo plane writes (x256 scale) ======
#define H1P 2624   // 8 patches * 328
#define H2P 2304   // 32 rows * 72
__global__ __launch_bounds__(256, 4) void encoder7(
    const float* __restrict__ x,
    const float* __restrict__ w1, const float* __restrict__ b1,
    const float* __restrict__ b2, const float* __restrict__ b3,
    const float* __restrict__ rb1, const float* __restrict__ rb2,
    const float* __restrict__ pb,
    const unsigned short* __restrict__ ewh, const unsigned short* __restrict__ ewl,
    float* __restrict__ z, unsigned short* __restrict__ zh,
    unsigned short* __restrict__ zl) {
  __shared__ __align__(16) short arena[9856];   // 19712 B
  short* H1h = arena;                  // [8 pat][8 pos][32 ch], pos stride 40
  short* H1l = arena + H1P;
  short* H2h = arena + 2 * H1P;        // [32 m][64 ch], stride 72
  short* H2l = arena + 2 * H1P + H2P;
  short* T1h = arena;                  // [32 m][32 ch], stride 40 (H1 dead)
  short* T1l = arena + 1280;
  float* XS  = (float*)(arena + 2 * H1P);  // [8][16] f32 (H2h head, dead pre-conv2)

  const int tid = threadIdx.x;
  const int wave = tid >> 6, lane = tid & 63, quad = lane >> 4, l15 = lane & 15;
  const int mt = wave >> 1, nh = wave & 1;     // m-tile, nt-half
  const size_t pbase = (size_t)blockIdx.x * 8;
  const h8 zh8 = {0, 0, 0, 0, 0, 0, 0, 0};
  const f32x4 zf4 = {0.f, 0.f, 0.f, 0.f};

  h8 w2h[4][2], w2l[4][2];
#pragma unroll
  for (int t = 0; t < 4; ++t)
#pragma unroll
    for (int j = 0; j < 2; ++j) {
      const int wb = EW2_OFF + (t * 64 + (nh * 2 + j) * 16 + l15) * 32 + quad * 8;
      w2h[t][j] = *reinterpret_cast<const h8*>(ewh + wb);
      w2l[t][j] = *reinterpret_cast<const h8*>(ewl + wb);
    }

  if (tid < 32) {
    int pp = tid >> 2, i = (tid & 3) * 4;
    *reinterpret_cast<float4*>(&XS[pp * 16 + i]) =
        *reinterpret_cast<const float4*>(x + (pbase + pp) * 16 + i);
  }
  __syncthreads();

  { // ---- conv1 (VALU fp32) ----
    const int pp = tid >> 5, op = (tid >> 2) & 7, qt = tid & 3;
    float xv[4];
#pragma unroll
    for (int kk = 0; kk < 4; ++kk) {
      int ip = 2 * op + kk - 1;
      xv[kk] = (ip >= 0 && ip < 16) ? XS[pp * 16 + ip] : 0.f;
    }
    bf8 sh, sl;
#pragma unroll
    for (int c = 0; c < 8; ++c) {
      int co = qt * 8 + c;
      float4 wv = *reinterpret_cast<const float4*>(w1 + co * 4);
      float a = b1[co] + xv[0] * wv.x + xv[1] * wv.y + xv[2] * wv.z + xv[3] * wv.w;
      a = fmaxf(a, 0.f);
      short hs, ls;
      splitf16(a, hs, ls);
      sh[c] = hs; sl[c] = ls;
    }
    const int off = pp * 328 + op * 40 + qt * 8;
    *reinterpret_cast<bf8*>(&H1h[off]) = sh;
    *reinterpret_cast<bf8*>(&H1l[off]) = sl;
  }
  __syncthreads();

  f32x4 h3keep[2];

  // ---- conv2 ----
  f32x4 acc2A[2] = {zf4, zf4};
  f32x4 acc2B[2] = {zf4, zf4};
  {
    const float bs2_0 = b2[nh * 32 + l15];
    const float bs2_1 = b2[nh * 32 + 16 + l15];
    const int patch = mt * 4 + (l15 >> 2), outp = l15 & 3;
#pragma unroll
    for (int t = 0; t < 4; ++t) {
      const int ip = 2 * outp + t - 1;
      const bool vld = (unsigned)ip < 8u;
      const int aoff = patch * 328 + (vld ? ip : 0) * 40 + quad * 8;
      h8 ah = *reinterpret_cast<const h8*>(&H1h[aoff]);
      h8 al = *reinterpret_cast<const h8*>(&H1l[aoff]);
      if (!vld) { ah = zh8; al = zh8; }
#pragma unroll
      for (int j = 0; j < 2; ++j) {
        acc2A[j] = __builtin_amdgcn_mfma_f32_16x16x32_f16(ah, w2h[t][j], acc2A[j], 0, 0, 0);
        acc2B[j] = __builtin_amdgcn_mfma_f32_16x16x32_f16(ah, w2l[t][j], acc2B[j], 0, 0, 0);
        acc2B[j] = __builtin_amdgcn_mfma_f32_16x16x32_f16(al, w2h[t][j], acc2B[j], 0, 0, 0);
      }
    }
    h8 w3h[3][2][2], w3l[3][2][2];       // [t][ks][j]
#pragma unroll
    for (int t = 0; t < 3; ++t)
#pragma unroll
      for (int ks = 0; ks < 2; ++ks)
#pragma unroll
        for (int j = 0; j < 2; ++j) {
          const int wb = EW3_OFF + (t * 64 + (nh * 2 + j) * 16 + l15) * 64 + ks * 32 + quad * 8;
          w3h[t][ks][j] = *reinterpret_cast<const h8*>(ewh + wb);
          w3l[t][ks][j] = *reinterpret_cast<const h8*>(ewl + wb);
        }
#pragma unroll
    for (int j = 0; j < 2; ++j) {
      const int col = (nh * 2 + j) * 16 + l15;
      const float bs = (j == 0) ? bs2_0 : bs2_1;
#pragma unroll
      for (int r = 0; r < 4; ++r) {
        float v = fmaxf(acc2A[j][r] + acc2B[j][r] * (1.f / 4096.f) + bs, 0.f);
        short vh, vl;
        splitf16(v, vh, vl);
        const int m = mt * 16 + quad * 4 + r;
        H2h[m * 72 + col] = vh;
        H2l[m * 72 + col] = vl;
      }
    }
    __syncthreads();

    // ---- conv3 ----
    f32x4 accA[2] = {zf4, zf4};
    f32x4 accB[2] = {zf4, zf4};
    const float bs3_0 = b3[nh * 32 + l15];
    const float bs3_1 = b3[nh * 32 + 16 + l15];
    const int pos = l15 & 3;
#pragma unroll
    for (int t = 0; t < 3; ++t) {
      const int ip = pos + t - 1;
      const bool vld = (unsigned)ip < 4u;
      const int row = patch * 4 + (vld ? ip : 0);
#pragma unroll
      for (int ks = 0; ks < 2; ++ks) {
        const int aoff = row * 72 + ks * 32 + quad * 8;
        h8 ah = *reinterpret_cast<const h8*>(&H2h[aoff]);
        h8 al = *reinterpret_cast<const h8*>(&H2l[aoff]);
        if (!vld) { ah = zh8; al = zh8; }
#pragma unroll
        for (int j = 0; j < 2; ++j) {
          accA[j] = __builtin_amdgcn_mfma_f32_16x16x32_f16(ah, w3h[t][ks][j], accA[j], 0, 0, 0);
          accB[j] = __builtin_amdgcn_mfma_f32_16x16x32_f16(ah, w3l[t][ks][j], accB[j], 0, 0, 0);
          accB[j] = __builtin_amdgcn_mfma_f32_16x16x32_f16(al, w3h[t][ks][j], accB[j], 0, 0, 0);
        }
      }
    }
    __syncthreads();
#pragma unroll
    for (int j = 0; j < 2; ++j) {
      const int col = (nh * 2 + j) * 16 + l15;
      const float bs = (j == 0) ? bs3_0 : bs3_1;
#pragma unroll
      for (int r = 0; r < 4; ++r) {
        float v = accA[j][r] + accB[j][r] * (1.f / 4096.f) + bs;
        h3keep[j][r] = v;
        short vh, vl;
        splitf16(fmaxf(v, 0.f), vh, vl);
        const int m = mt * 16 + quad * 4 + r;
        H2h[m * 72 + col] = vh;
        H2l[m * 72 + col] = vl;
      }
    }
  }
  __syncthreads();

  for (int rl = 0; rl < 2; ++rl) {
    { // ---- res stage a ----
      h8 wah[3][2], wal[3][2];
#pragma unroll
      for (int t = 0; t < 3; ++t)
#pragma unroll
        for (int ks = 0; ks < 2; ++ks) {
          const int wb = ERA_OFF + ((rl * 3 + t) * 32 + nh * 16 + l15) * 64 + ks * 32 + quad * 8;
          wah[t][ks] = *reinterpret_cast<const h8*>(ewh + wb);
          wal[t][ks] = *reinterpret_cast<const h8*>(ewl + wb);
        }
      const float bsa = rb1[rl * 32 + nh * 16 + l15];
      f32x4 accA = zf4, accB = zf4;
      const int patch = mt * 4 + (l15 >> 2), pos = l15 & 3;
#pragma unroll
      for (int t = 0; t < 3; ++t) {
        const int ip = pos + t - 1;
        const bool vld = (unsigned)ip < 4u;
        const int row = patch * 4 + (vld ? ip : 0);
#pragma unroll
        for (int ks = 0; ks < 2; ++ks) {
          const int aoff = row * 72 + ks * 32 + quad * 8;
          h8 ah = *reinterpret_cast<const h8*>(&H2h[aoff]);
          h8 al = *reinterpret_cast<const h8*>(&H2l[aoff]);
          if (!vld) { ah = zh8; al = zh8; }
          accA = __builtin_amdgcn_mfma_f32_16x16x32_f16(ah, wah[t][ks], accA, 0, 0, 0);
          accB = __builtin_amdgcn_mfma_f32_16x16x32_f16(ah, wal[t][ks], accB, 0, 0, 0);
          accB = __builtin_amdgcn_mfma_f32_16x16x32_f16(al, wah[t][ks], accB, 0, 0, 0);
        }
      }
      const int col = nh * 16 + l15;
#pragma unroll
      for (int r = 0; r < 4; ++r) {
        float v = fmaxf(accA[r] + accB[r] * (1.f / 4096.f) + bsa, 0.f);
        short vh, vl;
        splitf16(v, vh, vl);
        const int m = mt * 16 + quad * 4 + r;
        T1h[m * 40 + col] = vh;
        T1l[m * 40 + col] = vl;
      }
    }
    __syncthreads();
    { // ---- res stage b ----
      h8 wbh[2], wbl[2];
#pragma unroll
      for (int j = 0; j < 2; ++j) {
        const int wb = ERB_OFF + (rl * 64 + (nh * 2 + j) * 16 + l15) * 32 + quad * 8;
        wbh[j] = *reinterpret_cast<const h8*>(ewh + wb);
        wbl[j] = *reinterpret_cast<const h8*>(ewl + wb);
      }
      const float bsb0 = rb2[rl * 64 + nh * 32 + l15];
      const float bsb1 = rb2[rl * 64 + nh * 32 + 16 + l15];
      f32x4 accA[2] = {zf4, zf4};
      f32x4 accB[2] = {zf4, zf4};
      const int aoff = (mt * 16 + l15) * 40 + quad * 8;
      h8 ah = *reinterpret_cast<const h8*>(&T1h[aoff]);
      h8 al = *reinterpret_cast<const h8*>(&T1l[aoff]);
#pragma unroll
      for (int j = 0; j < 2; ++j) {
        accA[j] = __builtin_amdgcn_mfma_f32_16x16x32_f16(ah, wbh[j], accA[j], 0, 0, 0);
        accB[j] = __builtin_amdgcn_mfma_f32_16x16x32_f16(ah, wbl[j], accB[j], 0, 0, 0);
        accB[j] = __builtin_amdgcn_mfma_f32_16x16x32_f16(al, wbh[j], accB[j], 0, 0, 0);
      }
#pragma unroll
      for (int j = 0; j < 2; ++j) {
        const int col = (nh * 2 + j) * 16 + l15;
        const float bs = (j == 0) ? bsb0 : bsb1;
#pragma unroll
        for (int r = 0; r < 4; ++r) {
          float v = h3keep[j][r] + accA[j][r] + accB[j][r] * (1.f / 4096.f) + bs;
          h3keep[j][r] = v;
          short vh, vl;
          splitf16(fmaxf(v, 0.f), vh, vl);
          const int m = mt * 16 + quad * 4 + r;
          H2h[m * 72 + col] = vh;
          H2l[m * 72 + col] = vl;
        }
      }
    }
    __syncthreads();
  }

  { // ---- pre 1x1 -> z (fp32) + z planes (x256 scale for VQ) ----
    h8 wph[2], wpl[2];
#pragma unroll
    for (int ks = 0; ks < 2; ++ks) {
      const int wb = EPW_OFF + (nh * 16 + l15) * 64 + ks * 32 + quad * 8;
      wph[ks] = *reinterpret_cast<const h8*>(ewh + wb);
      wpl[ks] = *reinterpret_cast<const h8*>(ewl + wb);
    }
    const float bs = pb[nh * 16 + l15];
    f32x4 accA = zf4, accB = zf4;
    const int arow = mt * 16 + l15;
#pragma unroll
    for (int ks = 0; ks < 2; ++ks) {
      const int aoff = arow * 72 + ks * 32 + quad * 8;
      h8 ah = *reinterpret_cast<const h8*>(&H2h[aoff]);
      h8 al = *reinterpret_cast<const h8*>(&H2l[aoff]);
      accA = __builtin_amdgcn_mfma_f32_16x16x32_f16(ah, wph[ks], accA, 0, 0, 0);
      accB = __builtin_amdgcn_mfma_f32_16x16x32_f16(ah, wpl[ks], accB, 0, 0, 0);
      accB = __builtin_amdgcn_mfma_f32_16x16x32_f16(al, wph[ks], accB, 0, 0, 0);
    }
    const int pn = mt * 4 + quad;
    const int col = nh * 16 + l15;
    float ov[4];
#pragma unroll
    for (int r = 0; r < 4; ++r) ov[r] = accA[r] + accB[r] * (1.f / 4096.f) + bs;
    const size_t off = (pbase + pn) * 128 + col * 4;
    *reinterpret_cast<float4*>(z + off) = *reinterpret_cast<float4*>(ov);
    ushort4 h4, l4;
    unsigned short* hp = (unsigned short*)&h4;
    unsigned short* lp = (unsigned short*)&l4;
#pragma unroll
    for (int r = 0; r < 4; ++r) {
      short vh, vl;
      splitf16(ov[r] * 256.f, vh, vl);    // z*256 ~ 2.6e-2: f16-normal
      hp[r] = (unsigned short)vh;
      lp[r] = (unsigned short)vl;
    }
    *reinterpret_cast<ushort4*>(&zh[off]) = h4;
    *reinterpret_cast<ushort4*>(&zl[off]) = l4;
  }
}

// =============== weight pre-split: fp32 -> hi/lo bf16 planes (once/launch) ===============
__global__ __launch_bounds__(256) void split_w(
    const float* __restrict__ qkv_w, const float* __restrict__ proj_w,
    const float* __restrict__ f1, const float* __restrict__ f2,
    const float* __restrict__ hw, unsigned short* __restrict__ wh,
    unsigned short* __restrict__ wl) {
  int i = blockIdx.x * 256 + threadIdx.x;
  float v;
  if (i < 196608) v = qkv_w[i];
  else if (i < 262144) v = proj_w[i - 196608];
  else if (i < 393216) v = f1[i - 262144];
  else if (i < 524288) v = f2[i - 393216];
  else v = hw[i - 524288];
  short h = f2bf(v);
  wh[i] = (unsigned short)h;
  wl[i] = (unsigned short)f2bf(v - bf2f(h));
}

// ====== VQ argmin v3: split-f16 MFMA GEMM z.cb^T + |c|^2 + fused argmin ======
// Planes carry z*256 and c*64 -> acc = 2^14 * z.c; s = acc/16384 (exact pow2).
// d = |c|^2 - 2s; order-preserving key; atomicMin (ties -> smallest j).
__global__ __launch_bounds__(256) void vq_argmin3(
    const unsigned short* __restrict__ Ahg, const unsigned short* __restrict__ Alg,
    const unsigned short* __restrict__ Bhg, const unsigned short* __restrict__ Blg,
    const float* __restrict__ cbf, unsigned long long* __restrict__ keys) {
  __shared__ short Ah[128 * 40], Al[128 * 40], Bh[64 * 40], Bl[64 * 40];
  __shared__ float cns[64];
  const int tid = threadIdx.x;
  const int n0 = blockIdx.x * 64, m0 = blockIdx.y * 128;
  const int wave = tid >> 6, lane = tid & 63, quad = lane >> 4, l15 = lane & 15;
  const f32x4 z4 = {0.f, 0.f, 0.f, 0.f};
  f32x4 accA[2][4], accB[2][4];
#pragma unroll
  for (int i = 0; i < 2; ++i)
#pragma unroll
    for (int j = 0; j < 4; ++j) { accA[i][j] = z4; accB[i][j] = z4; }
  { // |c|^2 for the block's 64 cols (fp32)
    const int lr = tid >> 2, q = tid & 3;
    const float4* bp = reinterpret_cast<const float4*>(cbf + (size_t)(n0 + lr) * 128 + q * 32);
    float s = 0.f;
#pragma unroll
    for (int e = 0; e < 8; ++e) {
      float4 v = bp[e];
      s += v.x * v.x + v.y * v.y + v.z * v.z + v.w * v.w;
    }
    s += __shfl_xor(s, 1); s += __shfl_xor(s, 2);
    if (q == 0) cns[lr] = s;
  }
  const int ra = tid >> 1, ha = (tid & 1) * 16;         // A: 128 rows, 16 shorts each
  const int rb = tid >> 2, hb = (tid & 3) * 8;          // B: 64 rows, 8 shorts each
  for (int k0 = 0; k0 < 128; k0 += 32) {
    {
      const size_t abase = (size_t)(m0 + ra) * 128 + k0 + ha;
      *reinterpret_cast<bf8*>(&Ah[ra * 40 + ha])     = *reinterpret_cast<const bf8*>(&Ahg[abase]);
      *reinterpret_cast<bf8*>(&Ah[ra * 40 + ha + 8]) = *reinterpret_cast<const bf8*>(&Ahg[abase + 8]);
      *reinterpret_cast<bf8*>(&Al[ra * 40 + ha])     = *reinterpret_cast<const bf8*>(&Alg[abase]);
      *reinterpret_cast<bf8*>(&Al[ra * 40 + ha + 8]) = *reinterpret_cast<const bf8*>(&Alg[abase + 8]);
      const size_t bbase = (size_t)(n0 + rb) * 128 + k0 + hb;
      *reinterpret_cast<bf8*>(&Bh[rb * 40 + hb]) = *reinterpret_cast<const bf8*>(&Bhg[bbase]);
      *reinterpret_cast<bf8*>(&Bl[rb * 40 + hb]) = *reinterpret_cast<const bf8*>(&Blg[bbase]);
    }
    __syncthreads();
    h8 af[2], afl[2], bfh[4], bfl[4];
#pragma unroll
    for (int mt = 0; mt < 2; ++mt) {
      int row = wave * 32 + mt * 16 + l15;
      af[mt]  = *reinterpret_cast<const h8*>(&Ah[row * 40 + quad * 8]);
      afl[mt] = *reinterpret_cast<const h8*>(&Al[row * 40 + quad * 8]);
    }
#pragma unroll
    for (int nt = 0; nt < 4; ++nt) {
      int row = nt * 16 + l15;
      bfh[nt] = *reinterpret_cast<const h8*>(&Bh[row * 40 + quad * 8]);
      bfl[nt] = *reinterpret_cast<const h8*>(&Bl[row * 40 + quad * 8]);
    }
#pragma unroll
    for (int nt = 0; nt < 4; ++nt)
#pragma unroll
      for (int mt = 0; mt < 2; ++mt) {
        accA[mt][nt] = __builtin_amdgcn_mfma_f32_16x16x32_f16(af[mt], bfh[nt], accA[mt][nt], 0, 0, 0);
        accB[mt][nt] = __builtin_amdgcn_mfma_f32_16x16x32_f16(af[mt], bfl[nt], accB[mt][nt], 0, 0, 0);
        accB[mt][nt] = __builtin_amdgcn_mfma_f32_16x16x32_f16(afl[mt], bfh[nt], accB[mt][nt], 0, 0, 0);
      }
    __syncthreads();
  }
#pragma unroll
  for (int mt = 0; mt < 2; ++mt)
#pragma unroll
    for (int r = 0; r < 4; ++r) {
      const int row = m0 + wave * 32 + mt * 16 + quad * 4 + r;
      unsigned long long key = ~0ull;
#pragma unroll
      for (int nt = 0; nt < 4; ++nt) {
        const int c16 = nt * 16 + l15;
        float s = (accA[mt][nt][r] + accB[mt][nt][r] * (1.f / 4096.f)) * (1.f / 16384.f);
        float dv = cns[c16] - 2.f * s;            // |c|^2 - 2 z.c
        unsigned u = __float_as_uint(dv);
        u = (u & 0x80000000u) ? ~u : (u | 0x80000000u);  // order-preserving
        unsigned long long k = ((unsigned long long)u << 32) | (unsigned)(n0 + c16);
        key = k < key ? k : key;
      }
#pragma unroll
      for (int off = 1; off < 16; off <<= 1) {
        unsigned long long o = __shfl_xor(key, off);
        key = o < key ? o : key;
      }
      if (l15 == 0) atomicMin(&keys[row], key);
    }
}

// ===== VQ part 3: gather q, loss partials, hh = q + pos (fp32 + split planes) =====
__global__ __launch_bounds__(256) void vq_gather3(
    const float* __restrict__ z, const float* __restrict__ cb,
    const float* __restrict__ pos, const unsigned long long* __restrict__ keys,
    float* __restrict__ hh, unsigned short* __restrict__ hh_h,
    unsigned short* __restrict__ hh_l, float* __restrict__ lpart,
    float* __restrict__ idx_out) {
  const int blk = blockIdx.x, tid = threadIdx.x;
  __shared__ int sidx[8];
  if (tid < 8) {
    unsigned long long k = keys[blk * 8 + tid];
    int id = (int)(unsigned)(k & 0xffffffffull);
    sidx[tid] = id;
    idx_out[blk * 8 + tid] = (float)id;
  }
  __syncthreads();
  const int p = tid >> 5, d = tid & 31;
  const size_t n = (size_t)blk * 8 + p;
  const int idx = sidx[p];
  float4 q = *reinterpret_cast<const float4*>(cb + (size_t)idx * 128 + d * 4);
  float4 zv = *reinterpret_cast<const float4*>(z + n * 128 + d * 4);
  float4 pv = *reinterpret_cast<const float4*>(pos + (size_t)(n & 511) * 128 + d * 4);
  float hv[4] = {q.x + pv.x, q.y + pv.y, q.z + pv.z, q.w + pv.w};
  *reinterpret_cast<float4*>(hh + n * 128 + d * 4) = *reinterpret_cast<float4*>(hv);
  ushort4 h4, l4;
  unsigned short* hp = (unsigned short*)&h4;
  unsigned short* lp = (unsigned short*)&l4;
#pragma unroll
  for (int e = 0; e < 4; ++e) {
    short hb = f2bf(hv[e]);
    hp[e] = (unsigned short)hb;
    lp[e] = (unsigned short)f2bf(hv[e] - bf2f(hb));
  }
  *reinterpret_cast<ushort4*>(&hh_h[n * 128 + d * 4]) = h4;
  *reinterpret_cast<ushort4*>(&hh_l[n * 128 + d * 4]) = l4;
  float dx = q.x - zv.x, dy = q.y - zv.y, dz = q.z - zv.z, dw = q.w - zv.w;
  float part = dx * dx + dy * dy + dz * dz + dw * dw;
#pragma unroll
  for (int o = 1; o < 64; o <<= 1) part += __shfl_xor(part, o);
  __shared__ float lred[4];
  if ((tid & 63) == 0) lred[tid >> 6] = part;
  __syncthreads();
  if (tid == 0) lpart[blk] = lred[0] + lred[1] + lred[2] + lred[3];
}

// ====== split-bf16 MFMA GEMM (pre-split inputs): C = A[M,128]*B[N,128]^T + bias ======
// tile 128(M) x 64(N).  ACT: 0=none 1=gelu.  SPLIT: 1 -> write hi/lo planes, 0 -> fp32.
template <int ACT, int SPLIT>
__global__ __launch_bounds__(256) void mgemm2(
    const unsigned short* __restrict__ Ahg, const unsigned short* __restrict__ Alg,
    const unsigned short* __restrict__ Bhg, const unsigned short* __restrict__ Blg,
    const float* __restrict__ bias, float* __restrict__ C,
    unsigned short* __restrict__ Ch, unsigned short* __restrict__ Cl, int N) {
  __shared__ short Ah[128 * 40], Al[128 * 40], Bh[64 * 40], Bl[64 * 40];
  const int tid = threadIdx.x;
  const int n0 = blockIdx.x * 64, m0 = blockIdx.y * 128;
  const int wave = tid >> 6, lane = tid & 63, quad = lane >> 4, l15 = lane & 15;
  const f32x4 z4 = {0.f, 0.f, 0.f, 0.f};
  f32x4 acc[2][4];
#pragma unroll
  for (int i = 0; i < 2; ++i)
#pragma unroll
    for (int j = 0; j < 4; ++j) acc[i][j] = z4;

  const int ra = tid >> 1, ha = (tid & 1) * 16;         // A: 128 rows, 16 shorts each
  const int rb = tid >> 2, hb = (tid & 3) * 8;          // B: 64 rows, 8 shorts each
  for (int k0 = 0; k0 < 128; k0 += 32) {
    {
      const size_t abase = (size_t)(m0 + ra) * 128 + k0 + ha;
      *reinterpret_cast<bf8*>(&Ah[ra * 40 + ha])     = *reinterpret_cast<const bf8*>(&Ahg[abase]);
      *reinterpret_cast<bf8*>(&Ah[ra * 40 + ha + 8]) = *reinterpret_cast<const bf8*>(&Ahg[abase + 8]);
      *reinterpret_cast<bf8*>(&Al[ra * 40 + ha])     = *reinterpret_cast<const bf8*>(&Alg[abase]);
      *reinterpret_cast<bf8*>(&Al[ra * 40 + ha + 8]) = *reinterpret_cast<const bf8*>(&Alg[abase + 8]);
      const size_t bbase = (size_t)(n0 + rb) * 128 + k0 + hb;
      *reinterpret_cast<bf8*>(&Bh[rb * 40 + hb]) = *reinterpret_cast<const bf8*>(&Bhg[bbase]);
      *reinterpret_cast<bf8*>(&Bl[rb * 40 + hb]) = *reinterpret_cast<const bf8*>(&Blg[bbase]);
    }
    __syncthreads();
    bf8 af[2], afl[2], bfh[4], bfl[4];
#pragma unroll
    for (int mt = 0; mt < 2; ++mt) {
      int row = wave * 32 + mt * 16 + l15;
      af[mt]  = *reinterpret_cast<const bf8*>(&Ah[row * 40 + quad * 8]);
      afl[mt] = *reinterpret_cast<const bf8*>(&Al[row * 40 + quad * 8]);
    }
#pragma unroll
    for (int nt = 0; nt < 4; ++nt) {
      int row = nt * 16 + l15;
      bfh[nt] = *reinterpret_cast<const bf8*>(&Bh[row * 40 + quad * 8]);
      bfl[nt] = *reinterpret_cast<const bf8*>(&Bl[row * 40 + quad * 8]);
    }
#pragma unroll
    for (int nt = 0; nt < 4; ++nt)
#pragma unroll
      for (int mt = 0; mt < 2; ++mt)
        acc[mt][nt] = __builtin_amdgcn_mfma_f32_16x16x32_bf16(af[mt], bfh[nt], acc[mt][nt], 0, 0, 0);
#pragma unroll
    for (int nt = 0; nt < 4; ++nt)
#pragma unroll
      for (int mt = 0; mt < 2; ++mt)
        acc[mt][nt] = __builtin_amdgcn_mfma_f32_16x16x32_bf16(af[mt], bfl[nt], acc[mt][nt], 0, 0, 0);
#pragma unroll
    for (int nt = 0; nt < 4; ++nt)
#pragma unroll
      for (int mt = 0; mt < 2; ++mt)
        acc[mt][nt] = __builtin_amdgcn_mfma_f32_16x16x32_bf16(afl[mt], bfh[nt], acc[mt][nt], 0, 0, 0);
    __syncthreads();
  }
#pragma unroll
  for (int nt = 0; nt < 4; ++nt) {
    int col = n0 + nt * 16 + l15;
    float bv = bias[col];
#pragma unroll
    for (int mt = 0; mt < 2; ++mt) {
      int rbase = m0 + wave * 32 + mt * 16 + quad * 4;
#pragma unroll
      for (int r = 0; r < 4; ++r) {
        float v = acc[mt][nt][r] + bv;
        if (ACT == 1) v = 0.5f * v * (1.f + erff(v * 0.7071067811865476f));
        if (SPLIT) {
          short hb_ = f2bf(v);
          Ch[(size_t)(rbase + r) * N + col] = (unsigned short)hb_;
          Cl[(size_t)(rbase + r) * N + col] = (unsigned short)f2bf(v - bf2f(hb_));
        } else {
          C[(size_t)(rbase + r) * N + col] = v;
        }
      }
    }
  }
}

// == split-bf16 MFMA GEMM + residual + LN (optionally + second/final LN) ==
// out = LN(A.B^T+bias+res)*g+b; FINAL=1: y = LN2(out)*g2+b2 -> planes only.
// tile 64(M) x 128(N).  K: 128 or 256.
template <int K, int FINAL>
__global__ __launch_bounds__(256) void mgemm_ln2(
    const unsigned short* __restrict__ Ahg, const unsigned short* __restrict__ Alg,
    const unsigned short* __restrict__ Bhg, const unsigned short* __restrict__ Blg,
    const float* __restrict__ bias, const float* __restrict__ res,
    const float* __restrict__ g, const float* __restrict__ bb,
    const float* __restrict__ g2, const float* __restrict__ bb2,
    float* __restrict__ C, unsigned short* __restrict__ Ch,
    unsigned short* __restrict__ Cl) {
  __shared__ short Ah[64 * 40], Al[64 * 40], Bh[128 * 40], Bl[128 * 40];
  const int tid = threadIdx.x;
  const int m0 = blockIdx.x * 64;
  const int wave = tid >> 6, lane = tid & 63, quad = lane >> 4, l15 = lane & 15;
  const f32x4 z4 = {0.f, 0.f, 0.f, 0.f};
  f32x4 acc[8];
#pragma unroll
  for (int j = 0; j < 8; ++j) acc[j] = z4;

  const int ra = tid >> 2, ha = (tid & 3) * 8;          // A: 64 rows, 8 shorts each
  const int rb = tid >> 1, hb = (tid & 1) * 16;         // B: 128 rows, 16 shorts each
  for (int k0 = 0; k0 < K; k0 += 32) {
    {
      const size_t abase = (size_t)(m0 + ra) * K + k0 + ha;
      *reinterpret_cast<bf8*>(&Ah[ra * 40 + ha]) = *reinterpret_cast<const bf8*>(&Ahg[abase]);
      *reinterpret_cast<bf8*>(&Al[ra * 40 + ha]) = *reinterpret_cast<const bf8*>(&Alg[abase]);
      const size_t bbase = (size_t)rb * K + k0 + hb;
      *reinterpret_cast<bf8*>(&Bh[rb * 40 + hb])     = *reinterpret_cast<const bf8*>(&Bhg[bbase]);
      *reinterpret_cast<bf8*>(&Bh[rb * 40 + hb + 8]) = *reinterpret_cast<const bf8*>(&Bhg[bbase + 8]);
      *reinterpret_cast<bf8*>(&Bl[rb * 40 + hb])     = *reinterpret_cast<const bf8*>(&Blg[bbase]);
      *reinterpret_cast<bf8*>(&Bl[rb * 40 + hb + 8]) = *reinterpret_cast<const bf8*>(&Blg[bbase + 8]);
    }
    __syncthreads();
    bf8 af, afl, bfh[8], bfl[8];
    {
      int row = wave * 16 + l15;
      af  = *reinterpret_cast<const bf8*>(&Ah[row * 40 + quad * 8]);
      afl = *reinterpret_cast<const bf8*>(&Al[row * 40 + quad * 8]);
    }
#pragma unroll
    for (int nt = 0; nt < 8; ++nt) {
      int row = nt * 16 + l15;
      bfh[nt] = *reinterpret_cast<const bf8*>(&Bh[row * 40 + quad * 8]);
      bfl[nt] = *reinterpret_cast<const bf8*>(&Bl[row * 40 + quad * 8]);
    }
#pragma unroll
    for (int nt = 0; nt < 8; ++nt)
      acc[nt] = __builtin_amdgcn_mfma_f32_16x16x32_bf16(af, bfh[nt], acc[nt], 0, 0, 0);
#pragma unroll
    for (int nt = 0; nt < 8; ++nt)
      acc[nt] = __builtin_amdgcn_mfma_f32_16x16x32_bf16(af, bfl[nt], acc[nt], 0, 0, 0);
#pragma unroll
    for (int nt = 0; nt < 8; ++nt)
      acc[nt] = __builtin_amdgcn_mfma_f32_16x16x32_bf16(afl, bfh[nt], acc[nt], 0, 0, 0);
    __syncthreads();
  }
  float bias_v[8], g_v[8], bb_v[8], g2_v[8], bb2_v[8];
#pragma unroll
  for (int nt = 0; nt < 8; ++nt) {
    int col = nt * 16 + l15;
    bias_v[nt] = bias[col]; g_v[nt] = g[col]; bb_v[nt] = bb[col];
    if (FINAL) { g2_v[nt] = g2[col]; bb2_v[nt] = bb2[col]; }
  }
  const int rbase = m0 + wave * 16 + quad * 4;
#pragma unroll
  for (int r = 0; r < 4; ++r) {
    const int row = rbase + r;
    float ov[8];
    float s = 0.f;
#pragma unroll
    for (int nt = 0; nt < 8; ++nt) {
      ov[nt] = acc[nt][r] + bias_v[nt] + res[(size_t)row * 128 + nt * 16 + l15];
      s += ov[nt];
    }
    s += __shfl_xor(s, 1); s += __shfl_xor(s, 2);
    s += __shfl_xor(s, 4); s += __shfl_xor(s, 8);
    float mean = s * 0.0078125f;
    float s2 = 0.f;
#pragma unroll
    for (int nt = 0; nt < 8; ++nt) { ov[nt] -= mean; s2 += ov[nt] * ov[nt]; }
    s2 += __shfl_xor(s2, 1); s2 += __shfl_xor(s2, 2);
    s2 += __shfl_xor(s2, 4); s2 += __shfl_xor(s2, 8);
    float rstd = rsqrtf(s2 * 0.0078125f + 1e-5f);
    if (FINAL) {
      float yv[8];
      float s3 = 0.f;
#pragma unroll
      for (int nt = 0; nt < 8; ++nt) { yv[nt] = ov[nt] * rstd * g_v[nt] + bb_v[nt]; s3 += yv[nt]; }
      s3 += __shfl_xor(s3, 1); s3 += __shfl_xor(s3, 2);
      s3 += __shfl_xor(s3, 4); s3 += __shfl_xor(s3, 8);
      float mean2 = s3 * 0.0078125f;
      float s4 = 0.f;
#pragma unroll
      for (int nt = 0; nt < 8; ++nt) { yv[nt] -= mean2; s4 += yv[nt] * yv[nt]; }
      s4 += __shfl_xor(s4, 1); s4 += __shfl_xor(s4, 2);
      s4 += __shfl_xor(s4, 4); s4 += __shfl_xor(s4, 8);
      float rstd2 = rsqrtf(s4 * 0.0078125f + 1e-5f);
#pragma unroll
      for (int nt = 0; nt < 8; ++nt) {
        float v = yv[nt] * rstd2 * g2_v[nt] + bb2_v[nt];
        size_t off = (size_t)row * 128 + nt * 16 + l15;
        short hb_ = f2bf(v);
        Ch[off] = (unsigned short)hb_;
        Cl[off] = (unsigned short)f2bf(v - bf2f(hb_));
      }
    } else {
#pragma unroll
      for (int nt = 0; nt < 8; ++nt) {
        float v = ov[nt] * rstd * g_v[nt] + bb_v[nt];
        size_t off = (size_t)row * 128 + nt * 16 + l15;
        C[off] = v;
        short hb_ = f2bf(v);
        Ch[off] = (unsigned short)hb_;
        Cl[off] = (unsigned short)f2bf(v - bf2f(hb_));
      }
    }
  }
}

// ====== MFMA flash attention: block per (qt,h,b); reads/writes split planes ======
__global__ __launch_bounds__(256) void attn3(
    const unsigned short* __restrict__ qh_, const unsigned short* __restrict__ ql_,
    unsigned short* __restrict__ oh, unsigned short* __restrict__ ol) {
  const int qt = blockIdx.x, h = blockIdx.y, b = blockIdx.z;
  __shared__ short Kh[64 * 40], Kl[64 * 40];     // [key][d]
  __shared__ short Vth[32 * 72], Vtl[32 * 72];   // [d][key]
  __shared__ float Ss[64 * 72];
  __shared__ float ms[64], ls[64], alphas[64];
  const int tid = threadIdx.x;
  const int wave = tid >> 6, lane = tid & 63, quad = lane >> 4, l15 = lane & 15;
  const size_t tbase = (size_t)b * 512 + qt * 64;
  bf8 qfh, qfl;
  {
    const size_t qoff = (tbase + wave * 16 + l15) * 384 + h * 32 + quad * 8;
    qfh = *reinterpret_cast<const bf8*>(&qh_[qoff]);
    qfl = *reinterpret_cast<const bf8*>(&ql_[qoff]);
  }
  if (tid < 64) { ms[tid] = -1e30f; ls[tid] = 0.f; }
  const f32x4 z4 = {0.f, 0.f, 0.f, 0.f};
  f32x4 o[2] = {z4, z4};
  const float scale = 0.17677669529663687f;  // 1/sqrt(32)
  const int sr = tid >> 2, sc8 = (tid & 3) * 8;
  for (int kt = 0; kt <= qt; ++kt) {
    const size_t kbase = (size_t)b * 512 + kt * 64;
    {
      const size_t koff = (kbase + sr) * 384 + 128 + h * 32 + sc8;
      *reinterpret_cast<bf8*>(&Kh[sr * 40 + sc8]) = *reinterpret_cast<const bf8*>(&qh_[koff]);
      *reinterpret_cast<bf8*>(&Kl[sr * 40 + sc8]) = *reinterpret_cast<const bf8*>(&ql_[koff]);
      const size_t voff = (kbase + sr) * 384 + 256 + h * 32 + sc8;
      bf8 vh8 = *reinterpret_cast<const bf8*>(&qh_[voff]);
      bf8 vl8 = *reinterpret_cast<const bf8*>(&ql_[voff]);
#pragma unroll
      for (int j = 0; j < 8; ++j) {
        Vth[(sc8 + j) * 72 + sr] = vh8[j];
        Vtl[(sc8 + j) * 72 + sr] = vl8[j];
      }
    }
    __syncthreads();
    {
#pragma unroll
      for (int nt = 0; nt < 4; ++nt) {
        const int krow = nt * 16 + l15;
        bf8 kfh = *reinterpret_cast<const bf8*>(&Kh[krow * 40 + quad * 8]);
        bf8 kfl = *reinterpret_cast<const bf8*>(&Kl[krow * 40 + quad * 8]);
        f32x4 s = z4;
        s = __builtin_amdgcn_mfma_f32_16x16x32_bf16(qfh, kfh, s, 0, 0, 0);
        s = __builtin_amdgcn_mfma_f32_16x16x32_bf16(qfh, kfl, s, 0, 0, 0);
        s = __builtin_amdgcn_mfma_f32_16x16x32_bf16(qfl, kfh, s, 0, 0, 0);
#pragma unroll
        for (int r = 0; r < 4; ++r) {
          int row64 = wave * 16 + quad * 4 + r;
          int col64 = nt * 16 + l15;
          float v = s[r] * scale;
          if (kt == qt && col64 > row64) v += -1e9f;
          Ss[row64 * 72 + col64] = v;
        }
      }
    }
    __syncthreads();
    {
      const int i = tid >> 2, q = tid & 3;
      float mx = -3.4e38f;
      float4 pv[4];
#pragma unroll
      for (int t = 0; t < 4; ++t) {
        pv[t] = *reinterpret_cast<const float4*>(&Ss[i * 72 + q * 16 + t * 4]);
        mx = fmaxf(mx, fmaxf(fmaxf(pv[t].x, pv[t].y), fmaxf(pv[t].z, pv[t].w)));
      }
      mx = fmaxf(mx, __shfl_xor(mx, 1));
      mx = fmaxf(mx, __shfl_xor(mx, 2));
      float mold = ms[i];
      mx = fmaxf(mx, mold);
      float sum = 0.f;
#pragma unroll
      for (int t = 0; t < 4; ++t) {
        pv[t].x = __expf(pv[t].x - mx); pv[t].y = __expf(pv[t].y - mx);
        pv[t].z = __expf(pv[t].z - mx); pv[t].w = __expf(pv[t].w - mx);
        sum += pv[t].x + pv[t].y + pv[t].z + pv[t].w;
        *reinterpret_cast<float4*>(&Ss[i * 72 + q * 16 + t * 4]) = pv[t];
      }
      sum += __shfl_xor(sum, 1);
      sum += __shfl_xor(sum, 2);
      if (q == 0) {
        float alpha = __expf(mold - mx);
        ls[i] = ls[i] * alpha + sum;
        ms[i] = mx;
        alphas[i] = alpha;
      }
    }
    __syncthreads();
    {
      bf8 ph[2], pl[2];
#pragma unroll
      for (int c = 0; c < 2; ++c) {
        const float* pp = &Ss[(wave * 16 + l15) * 72 + c * 32 + quad * 8];
        float4 p0 = *reinterpret_cast<const float4*>(pp);
        float4 p1 = *reinterpret_cast<const float4*>(pp + 4);
        float pf[8] = {p0.x, p0.y, p0.z, p0.w, p1.x, p1.y, p1.z, p1.w};
#pragma unroll
        for (int j = 0; j < 8; ++j) {
          short hb_ = f2bf(pf[j]);
          ph[c][j] = hb_;
          pl[c][j] = f2bf(pf[j] - bf2f(hb_));
        }
      }
      float a0 = alphas[wave * 16 + quad * 4 + 0];
      float a1 = alphas[wave * 16 + quad * 4 + 1];
      float a2 = alphas[wave * 16 + quad * 4 + 2];
      float a3 = alphas[wave * 16 + quad * 4 + 3];
#pragma unroll
      for (int dt = 0; dt < 2; ++dt) {
        o[dt][0] *= a0; o[dt][1] *= a1; o[dt][2] *= a2; o[dt][3] *= a3;
#pragma unroll
        for (int c = 0; c < 2; ++c) {
          const int vrow = dt * 16 + l15;
          bf8 vfh = *reinterpret_cast<const bf8*>(&Vth[vrow * 72 + c * 32 + quad * 8]);
          bf8 vfl = *reinterpret_cast<const bf8*>(&Vtl[vrow * 72 + c * 32 + quad * 8]);
          o[dt] = __builtin_amdgcn_mfma_f32_16x16x32_bf16(ph[c], vfh, o[dt], 0, 0, 0);
          o[dt] = __builtin_amdgcn_mfma_f32_16x16x32_bf16(ph[c], vfl, o[dt], 0, 0, 0);
          o[dt] = __builtin_amdgcn_mfma_f32_16x16x32_bf16(pl[c], vfh, o[dt], 0, 0, 0);
        }
      }
    }
    __syncthreads();
  }
#pragma unroll
  for (int r = 0; r < 4; ++r) {
    float inv = 1.f / ls[wave * 16 + quad * 4 + r];
    size_t row = tbase + wave * 16 + quad * 4 + r;
#pragma unroll
    for (int dt = 0; dt < 2; ++dt) {
      float v = o[dt][r] * inv;
      short hb_ = f2bf(v);
      size_t off = row * 128 + h * 32 + dt * 16 + l15;
      oh[off] = (unsigned short)hb_;
      ol[off] = (unsigned short)f2bf(v - bf2f(hb_));
    }
  }
}

__global__ __launch_bounds__(256) void loss_finalize2(const float* __restrict__ lp,
                                                      float* __restrict__ out) {
  float s = 0.f;
  for (int i = threadIdx.x; i < 2048; i += 256) s += lp[i];
#pragma unroll
  for (int o = 1; o < 64; o <<= 1) s += __shfl_xor(s, o);
  __shared__ float red[4];
  if ((threadIdx.x & 63) == 0) red[threadIdx.x >> 6] = s;
  __syncthreads();
  if (threadIdx.x == 0)
    out[0] = 1.25f * (red[0] + red[1] + red[2] + red[3]) / 2097152.0f;
}

extern "C" void kernel_launch(void* const* d_in, const int* in_sizes, int n_in,
                              void* d_out, int out_size, void* d_ws, size_t ws_size,
                              hipStream_t stream) {
  const float* x      = (const float*)d_in[0];
  const float* enc_w1 = (const float*)d_in[1];
  const float* enc_b1 = (const float*)d_in[2];
  const float* enc_w2 = (const float*)d_in[3];
  const float* enc_b2 = (const float*)d_in[4];
  const float* enc_w3 = (const float*)d_in[5];
  const float* enc_b3 = (const float*)d_in[6];
  const float* res_w1 = (const float*)d_in[7];
  const float* res_b1 = (const float*)d_in[8];
  const float* res_w2 = (const float*)d_in[9];
  const float* res_b2 = (const float*)d_in[10];
  const float* pre_w  = (const float*)d_in[11];
  const float* pre_b  = (const float*)d_in[12];
  const float* codebook = (const float*)d_in[13];
  const float* pos_emb  = (const float*)d_in[14];
  const float* qkv_w  = (const float*)d_in[15];
  const float* qkv_b  = (const float*)d_in[16];
  const float* proj_w = (const float*)d_in[17];
  const float* proj_b = (const float*)d_in[18];
  const float* ln1_g  = (const float*)d_in[19];
  const float* ln1_b  = (const float*)d_in[20];
  const float* ln2_g  = (const float*)d_in[21];
  const float* ln2_b  = (const float*)d_in[22];
  const float* ffn_w1 = (const float*)d_in[23];
  const float* ffn_b1 = (const float*)d_in[24];
  const float* ffn_w2 = (const float*)d_in[25];
  const float* ffn_b2 = (const float*)d_in[26];
  const float* fin_g  = (const float*)d_in[27];
  const float* fin_b  = (const float*)d_in[28];
  const float* head_w = (const float*)d_in[29];
  const float* head_b = (const float*)d_in[30];

  float* out = (float*)d_out;
  float* ws  = (float*)d_ws;

  // ws: keys(32768f) | lpart(2048) | pad | wh/wl planes | hhln planes
  unsigned long long* keys = (unsigned long long*)ws;
  float* lpart = ws + 32768;
  unsigned short* wh = (unsigned short*)(ws + 36864);
  unsigned short* wl = (unsigned short*)(ws + 36864 + 327680);
  unsigned short* hhln_h = (unsigned short*)(ws + 692224);
  unsigned short* hhln_l = (unsigned short*)(ws + 692224 + 1048576);

  // d_out scratch overlay (float offsets; dead before head GEMM)
  float* zf = out;                                            // [0 .. 2^21)
  float* hh = out + 2097152;                                  // [2^21 .. 2^22)
  unsigned short* hh_h   = (unsigned short*)(out + 4194304);
  unsigned short* hh_l   = (unsigned short*)(out + 5242880);
  unsigned short* qkvb_h = (unsigned short*)(out + 6291456);
  unsigned short* qkvb_l = (unsigned short*)(out + 9437184);
  unsigned short* oatt_h = (unsigned short*)(out + 12582912);
  unsigned short* oatt_l = (unsigned short*)(out + 13631488);
  unsigned short* fbuf_h = (unsigned short*)(out + 0);        // overlays zf (dead)
  unsigned short* fbuf_l = (unsigned short*)(out + 14680064);

  // encoder weight planes overlay qkvb region (dead until first mgemm2)
  unsigned short* ewh = (unsigned short*)(out + 6291456);
  unsigned short* ewl = ewh + EWTOT;                          // ends < out+6330368

  // z planes (dead after vq_argmin3, before qkv writes qkvb region)
  unsigned short* zh = (unsigned short*)(out + 6340608);      // 2M ushorts
  unsigned short* zl = (unsigned short*)(out + 7389184);      // ends 8437760
  // codebook planes + |c|^2 (overlay oatt region, dead until attn3)
  unsigned short* cbh = (unsigned short*)(out + 12582912);
  unsigned short* cbl = (unsigned short*)(out + 12648448);
  float* cnbuf = out + 12713984;

  const int W_QKV = 0, W_PROJ = 196608, W_F1 = 262144, W_F2 = 393216, W_HEAD = 524288;

  hipMemsetAsync(keys, 0xFF, NPATCH * sizeof(unsigned long long), stream);

  enc_split<<<152, 256, 0, stream>>>(enc_w2, enc_w3, res_w1, res_w2, pre_w, ewh, ewl);
  cb_split<<<512, 256, 0, stream>>>(codebook, cbh, cbl, cnbuf);
  encoder7<<<2048, 256, 0, stream>>>(x, enc_w1, enc_b1, enc_b2, enc_b3,
                                     res_b1, res_b2, pre_b, ewh, ewl, zf, zh, zl);
  split_w<<<2560, 256, 0, stream>>>(qkv_w, proj_w, ffn_w1, ffn_w2, head_w, wh, wl);
  vq_argmin3<<<dim3(16, 128), 256, 0, stream>>>(zh, zl, cbh, cbl, codebook, keys);
  vq_gather3<<<2048, 256, 0, stream>>>(zf, codebook, pos_emb, keys, hh, hh_h, hh_l,
                                       lpart, out + IDX_OFF);
  for (int i = 0; i < 4; ++i) {
    mgemm2<0, 1><<<dim3(6, 128), 256, 0, stream>>>(
        hh_h, hh_l, wh + W_QKV + i * 49152, wl + W_QKV + i * 49152,
        qkv_b + i * 384, nullptr, qkvb_h, qkvb_l, 384);
    attn3<<<dim3(8, 4, 32), 256, 0, stream>>>(qkvb_h, qkvb_l, oatt_h, oatt_l);
    mgemm_ln2<128, 0><<<256, 256, 0, stream>>>(
        oatt_h, oatt_l, wh + W_PROJ + i * 16384, wl + W_PROJ + i * 16384,
        proj_b + i * 128, hh, ln1_g + i * 128, ln1_b + i * 128,
        nullptr, nullptr, hh, hh_h, hh_l);
    mgemm2<1, 1><<<dim3(4, 128), 256, 0, stream>>>(
        hh_h, hh_l, wh + W_F1 + i * 32768, wl + W_F1 + i * 32768,
        ffn_b1 + i * 256, nullptr, fbuf_h, fbuf_l, 256);
    if (i < 3) {
      mgemm_ln2<256, 0><<<256, 256, 0, stream>>>(
          fbuf_h, fbuf_l, wh + W_F2 + i * 32768, wl + W_F2 + i * 32768,
          ffn_b2 + i * 128, hh, ln2_g + i * 128, ln2_b + i * 128,
          nullptr, nullptr, hh, hh_h, hh_l);
    } else {
      mgemm_ln2<256, 1><<<256, 256, 0, stream>>>(
          fbuf_h, fbuf_l, wh + W_F2 + i * 32768, wl + W_F2 + i * 32768,
          ffn_b2 + i * 128, hh, ln2_g + i * 128, ln2_b + i * 128,
          fin_g, fin_b, hh, hhln_h, hhln_l);
    }
  }
  mgemm2<0, 0><<<dim3(16, 128), 256, 0, stream>>>(
      hhln_h, hhln_l, wh + W_HEAD, wl + W_HEAD, head_b, out, nullptr, nullptr, 1024);
  loss_finalize2<<<1, 256, 0, stream>>>(lpart, out + LOSS_OFF);
}

// Round 7
// 534.308 us; speedup vs baseline: 1.3484x; 1.2518x over previous
//
#include <hip/hip_runtime.h>
#include <math.h>

// ---- problem constants ----
#define NPATCH 16384          // B * T / P
#define SEQ    512            // T / P
#define LOSS_OFF 16777216
#define IDX_OFF  16777217

typedef short bf8 __attribute__((ext_vector_type(8)));    // 8 bf16 (4 VGPRs)
typedef _Float16 h8 __attribute__((ext_vector_type(8)));  // 8 f16 (4 VGPRs)
typedef float f32x4 __attribute__((ext_vector_type(4)));  // MFMA acc

__device__ inline short f2bf(float x) {          // fp32 -> bf16 RNE
  unsigned u = __float_as_uint(x);
  u += 0x7fffu + ((u >> 16) & 1u);
  return (short)(u >> 16);
}
__device__ inline float bf2f(short h) {
  return __uint_as_float(((unsigned)(unsigned short)h) << 16);
}

// f16 split with 4096-scaled lo plane (encoder + VQ only).  hi forced to 0
// below f16-normal; VQ operands pre-scaled by pow2 so clamp never fires (R5).
__device__ inline void splitf16(float v, short& hi, short& lo) {
  _Float16 h = (fabsf(v) < 6.1035156e-5f) ? (_Float16)0.f : (_Float16)v;
  hi = __builtin_bit_cast(short, h);
  lo = __builtin_bit_cast(short, (_Float16)((v - (float)h) * 4096.f));
}

// encoder weight plane offsets (in halfs) inside ewh/ewl
#define EW2_OFF 0        // [t][co][ci]  4*64*32  = 8192
#define EW3_OFF 8192     // [t][co][ci]  3*64*64  = 12288
#define ERA_OFF 20480    // [rl][t][co][ci] 2*3*32*64 = 12288
#define ERB_OFF 32768    // [rl][co][ci] 2*64*32  = 4096
#define EPW_OFF 36864    // [co][ci]     32*64    = 2048
#define EWTOT   38912

// ---- pre-split + transpose encoder weights into f16 hi / scaled-lo planes ----
__global__ __launch_bounds__(256) void enc_split(
    const float* __restrict__ w2, const float* __restrict__ w3,
    const float* __restrict__ rw1, const float* __restrict__ rw2,
    const float* __restrict__ pw,
    unsigned short* __restrict__ eh, unsigned short* __restrict__ el) {
  int i = blockIdx.x * 256 + threadIdx.x;     // 0..38911 exactly
  float v;
  if (i < 8192) {                 // EW2 [t][co][ci] <- w2[co][ci][t]
    int t = i >> 11, co = (i >> 5) & 63, ci = i & 31;
    v = w2[(co * 32 + ci) * 4 + t];
  } else if (i < 20480) {         // EW3 [t][co][ci] <- w3[co][ci][t]
    int j = i - 8192;
    int t = j >> 12, co = (j >> 6) & 63, ci = j & 63;
    v = w3[(co * 64 + ci) * 3 + t];
  } else if (i < 32768) {         // ERA [rl][t][co][ci] <- rw1[rl][co][ci][t]
    int j = i - 20480;
    int rl = j / 6144; j -= rl * 6144;
    int t = j >> 11, co = (j >> 6) & 31, ci = j & 63;
    v = rw1[((rl * 32 + co) * 64 + ci) * 3 + t];
  } else if (i < 36864) {         // ERB [rl][co][ci] <- rw2
    int j = i - 32768;
    int rl = j >> 11, co = (j >> 5) & 63, ci = j & 31;
    v = rw2[(rl * 64 + co) * 32 + ci];
  } else {                        // EPW [co][ci] <- pw
    int j = i - 36864;
    int co = j >> 6, ci = j & 63;
    v = pw[co * 64 + ci];
  }
  short hh_, ll_;
  splitf16(v, hh_, ll_);
  eh[i] = (unsigned short)hh_;
  el[i] = (unsigned short)ll_;
}

// ---- codebook split (x64 pre-scale) + fp32 |c|^2 ----
__global__ __launch_bounds__(256) void cb_split(
    const float* __restrict__ cb, unsigned short* __restrict__ ch,
    unsigned short* __restrict__ cl, float* __restrict__ cn) {
  const int i = blockIdx.x * 256 + threadIdx.x;   // 0..131071 exactly (512 blocks)
  float v = cb[i];
  short hi, lo;
  splitf16(v * 64.f, hi, lo);                     // c*64: f16-normal
  ch[i] = (unsigned short)hi;
  cl[i] = (unsigned short)lo;
  float s = v * v;                                // row = i>>7 (2 rows/block)
#pragma unroll
  for (int o = 1; o < 64; o <<= 1) s += __shfl_xor(s, o);
  __shared__ float red[4];
  if ((threadIdx.x & 63) == 0) red[threadIdx.x >> 6] = s;
  __syncthreads();
  if (threadIdx.x == 0)   cn[i >> 7] = red[0] + red[1];
  if (threadIdx.x == 128) cn[i >> 7] = red[2] + red[3];
}

// ====== encoder v7 (proven 73us config) + z hi/lo plane writes (x256 scale) ======
#define H1P 2624   // 8 patches * 328
#define H2P 2304   // 32 rows * 72
__global__ __launch_bounds__(256, 4) void encoder7(
    const float* __restrict__ x,
    const float* __restrict__ w1, const float* __restrict__ b1,
    const float* __restrict__ b2, const float* __restrict__ b3,
    const float* __restrict__ rb1, const float* __restrict__ rb2,
    const float* __restrict__ pb,
    const unsigned short* __restrict__ ewh, const unsigned short* __restrict__ ewl,
    float* __restrict__ z, unsigned short* __restrict__ zh,
    unsigned short* __restrict__ zl) {
  __shared__ __align__(16) short arena[9856];   // 19712 B
  short* H1h = arena;                  // [8 pat][8 pos][32 ch], pos stride 40
  short* H1l = arena + H1P;
  short* H2h = arena + 2 * H1P;        // [32 m][64 ch], stride 72
  short* H2l = arena + 2 * H1P + H2P;
  short* T1h = arena;                  // [32 m][32 ch], stride 40 (H1 dead)
  short* T1l = arena + 1280;
  float* XS  = (float*)(arena + 2 * H1P);  // [8][16] f32 (H2h head, dead pre-conv2)

  const int tid = threadIdx.x;
  const int wave = tid >> 6, lane = tid & 63, quad = lane >> 4, l15 = lane & 15;
  const int mt = wave >> 1, nh = wave & 1;     // m-tile, nt-half
  const size_t pbase = (size_t)blockIdx.x * 8;
  const h8 zh8 = {0, 0, 0, 0, 0, 0, 0, 0};
  const f32x4 zf4 = {0.f, 0.f, 0.f, 0.f};

  h8 w2h[4][2], w2l[4][2];
#pragma unroll
  for (int t = 0; t < 4; ++t)
#pragma unroll
    for (int j = 0; j < 2; ++j) {
      const int wb = EW2_OFF + (t * 64 + (nh * 2 + j) * 16 + l15) * 32 + quad * 8;
      w2h[t][j] = *reinterpret_cast<const h8*>(ewh + wb);
      w2l[t][j] = *reinterpret_cast<const h8*>(ewl + wb);
    }

  if (tid < 32) {
    int pp = tid >> 2, i = (tid & 3) * 4;
    *reinterpret_cast<float4*>(&XS[pp * 16 + i]) =
        *reinterpret_cast<const float4*>(x + (pbase + pp) * 16 + i);
  }
  __syncthreads();

  { // ---- conv1 (VALU fp32) ----
    const int pp = tid >> 5, op = (tid >> 2) & 7, qt = tid & 3;
    float xv[4];
#pragma unroll
    for (int kk = 0; kk < 4; ++kk) {
      int ip = 2 * op + kk - 1;
      xv[kk] = (ip >= 0 && ip < 16) ? XS[pp * 16 + ip] : 0.f;
    }
    bf8 sh, sl;
#pragma unroll
    for (int c = 0; c < 8; ++c) {
      int co = qt * 8 + c;
      float4 wv = *reinterpret_cast<const float4*>(w1 + co * 4);
      float a = b1[co] + xv[0] * wv.x + xv[1] * wv.y + xv[2] * wv.z + xv[3] * wv.w;
      a = fmaxf(a, 0.f);
      short hs, ls;
      splitf16(a, hs, ls);
      sh[c] = hs; sl[c] = ls;
    }
    const int off = pp * 328 + op * 40 + qt * 8;
    *reinterpret_cast<bf8*>(&H1h[off]) = sh;
    *reinterpret_cast<bf8*>(&H1l[off]) = sl;
  }
  __syncthreads();

  f32x4 h3keep[2];

  // ---- conv2 ----
  f32x4 acc2A[2] = {zf4, zf4};
  f32x4 acc2B[2] = {zf4, zf4};
  {
    const float bs2_0 = b2[nh * 32 + l15];
    const float bs2_1 = b2[nh * 32 + 16 + l15];
    const int patch = mt * 4 + (l15 >> 2), outp = l15 & 3;
#pragma unroll
    for (int t = 0; t < 4; ++t) {
      const int ip = 2 * outp + t - 1;
      const bool vld = (unsigned)ip < 8u;
      const int aoff = patch * 328 + (vld ? ip : 0) * 40 + quad * 8;
      h8 ah = *reinterpret_cast<const h8*>(&H1h[aoff]);
      h8 al = *reinterpret_cast<const h8*>(&H1l[aoff]);
      if (!vld) { ah = zh8; al = zh8; }
#pragma unroll
      for (int j = 0; j < 2; ++j) {
        acc2A[j] = __builtin_amdgcn_mfma_f32_16x16x32_f16(ah, w2h[t][j], acc2A[j], 0, 0, 0);
        acc2B[j] = __builtin_amdgcn_mfma_f32_16x16x32_f16(ah, w2l[t][j], acc2B[j], 0, 0, 0);
        acc2B[j] = __builtin_amdgcn_mfma_f32_16x16x32_f16(al, w2h[t][j], acc2B[j], 0, 0, 0);
      }
    }
    h8 w3h[3][2][2], w3l[3][2][2];       // [t][ks][j]
#pragma unroll
    for (int t = 0; t < 3; ++t)
#pragma unroll
      for (int ks = 0; ks < 2; ++ks)
#pragma unroll
        for (int j = 0; j < 2; ++j) {
          const int wb = EW3_OFF + (t * 64 + (nh * 2 + j) * 16 + l15) * 64 + ks * 32 + quad * 8;
          w3h[t][ks][j] = *reinterpret_cast<const h8*>(ewh + wb);
          w3l[t][ks][j] = *reinterpret_cast<const h8*>(ewl + wb);
        }
#pragma unroll
    for (int j = 0; j < 2; ++j) {
      const int col = (nh * 2 + j) * 16 + l15;
      const float bs = (j == 0) ? bs2_0 : bs2_1;
#pragma unroll
      for (int r = 0; r < 4; ++r) {
        float v = fmaxf(acc2A[j][r] + acc2B[j][r] * (1.f / 4096.f) + bs, 0.f);
        short vh, vl;
        splitf16(v, vh, vl);
        const int m = mt * 16 + quad * 4 + r;
        H2h[m * 72 + col] = vh;
        H2l[m * 72 + col] = vl;
      }
    }
    __syncthreads();

    // ---- conv3 ----
    f32x4 accA[2] = {zf4, zf4};
    f32x4 accB[2] = {zf4, zf4};
    const float bs3_0 = b3[nh * 32 + l15];
    const float bs3_1 = b3[nh * 32 + 16 + l15];
    const int pos = l15 & 3;
#pragma unroll
    for (int t = 0; t < 3; ++t) {
      const int ip = pos + t - 1;
      const bool vld = (unsigned)ip < 4u;
      const int row = patch * 4 + (vld ? ip : 0);
#pragma unroll
      for (int ks = 0; ks < 2; ++ks) {
        const int aoff = row * 72 + ks * 32 + quad * 8;
        h8 ah = *reinterpret_cast<const h8*>(&H2h[aoff]);
        h8 al = *reinterpret_cast<const h8*>(&H2l[aoff]);
        if (!vld) { ah = zh8; al = zh8; }
#pragma unroll
        for (int j = 0; j < 2; ++j) {
          accA[j] = __builtin_amdgcn_mfma_f32_16x16x32_f16(ah, w3h[t][ks][j], accA[j], 0, 0, 0);
          accB[j] = __builtin_amdgcn_mfma_f32_16x16x32_f16(ah, w3l[t][ks][j], accB[j], 0, 0, 0);
          accB[j] = __builtin_amdgcn_mfma_f32_16x16x32_f16(al, w3h[t][ks][j], accB[j], 0, 0, 0);
        }
      }
    }
    __syncthreads();
#pragma unroll
    for (int j = 0; j < 2; ++j) {
      const int col = (nh * 2 + j) * 16 + l15;
      const float bs = (j == 0) ? bs3_0 : bs3_1;
#pragma unroll
      for (int r = 0; r < 4; ++r) {
        float v = accA[j][r] + accB[j][r] * (1.f / 4096.f) + bs;
        h3keep[j][r] = v;
        short vh, vl;
        splitf16(fmaxf(v, 0.f), vh, vl);
        const int m = mt * 16 + quad * 4 + r;
        H2h[m * 72 + col] = vh;
        H2l[m * 72 + col] = vl;
      }
    }
  }
  __syncthreads();

  for (int rl = 0; rl < 2; ++rl) {
    { // ---- res stage a ----
      h8 wah[3][2], wal[3][2];
#pragma unroll
      for (int t = 0; t < 3; ++t)
#pragma unroll
        for (int ks = 0; ks < 2; ++ks) {
          const int wb = ERA_OFF + ((rl * 3 + t) * 32 + nh * 16 + l15) * 64 + ks * 32 + quad * 8;
          wah[t][ks] = *reinterpret_cast<const h8*>(ewh + wb);
          wal[t][ks] = *reinterpret_cast<const h8*>(ewl + wb);
        }
      const float bsa = rb1[rl * 32 + nh * 16 + l15];
      f32x4 accA = zf4, accB = zf4;
      const int patch = mt * 4 + (l15 >> 2), pos = l15 & 3;
#pragma unroll
      for (int t = 0; t < 3; ++t) {
        const int ip = pos + t - 1;
        const bool vld = (unsigned)ip < 4u;
        const int row = patch * 4 + (vld ? ip : 0);
#pragma unroll
        for (int ks = 0; ks < 2; ++ks) {
          const int aoff = row * 72 + ks * 32 + quad * 8;
          h8 ah = *reinterpret_cast<const h8*>(&H2h[aoff]);
          h8 al = *reinterpret_cast<const h8*>(&H2l[aoff]);
          if (!vld) { ah = zh8; al = zh8; }
          accA = __builtin_amdgcn_mfma_f32_16x16x32_f16(ah, wah[t][ks], accA, 0, 0, 0);
          accB = __builtin_amdgcn_mfma_f32_16x16x32_f16(ah, wal[t][ks], accB, 0, 0, 0);
          accB = __builtin_amdgcn_mfma_f32_16x16x32_f16(al, wah[t][ks], accB, 0, 0, 0);
        }
      }
      const int col = nh * 16 + l15;
#pragma unroll
      for (int r = 0; r < 4; ++r) {
        float v = fmaxf(accA[r] + accB[r] * (1.f / 4096.f) + bsa, 0.f);
        short vh, vl;
        splitf16(v, vh, vl);
        const int m = mt * 16 + quad * 4 + r;
        T1h[m * 40 + col] = vh;
        T1l[m * 40 + col] = vl;
      }
    }
    __syncthreads();
    { // ---- res stage b ----
      h8 wbh[2], wbl[2];
#pragma unroll
      for (int j = 0; j < 2; ++j) {
        const int wb = ERB_OFF + (rl * 64 + (nh * 2 + j) * 16 + l15) * 32 + quad * 8;
        wbh[j] = *reinterpret_cast<const h8*>(ewh + wb);
        wbl[j] = *reinterpret_cast<const h8*>(ewl + wb);
      }
      const float bsb0 = rb2[rl * 64 + nh * 32 + l15];
      const float bsb1 = rb2[rl * 64 + nh * 32 + 16 + l15];
      f32x4 accA[2] = {zf4, zf4};
      f32x4 accB[2] = {zf4, zf4};
      const int aoff = (mt * 16 + l15) * 40 + quad * 8;
      h8 ah = *reinterpret_cast<const h8*>(&T1h[aoff]);
      h8 al = *reinterpret_cast<const h8*>(&T1l[aoff]);
#pragma unroll
      for (int j = 0; j < 2; ++j) {
        accA[j] = __builtin_amdgcn_mfma_f32_16x16x32_f16(ah, wbh[j], accA[j], 0, 0, 0);
        accB[j] = __builtin_amdgcn_mfma_f32_16x16x32_f16(ah, wbl[j], accB[j], 0, 0, 0);
        accB[j] = __builtin_amdgcn_mfma_f32_16x16x32_f16(al, wbh[j], accB[j], 0, 0, 0);
      }
#pragma unroll
      for (int j = 0; j < 2; ++j) {
        const int col = (nh * 2 + j) * 16 + l15;
        const float bs = (j == 0) ? bsb0 : bsb1;
#pragma unroll
        for (int r = 0; r < 4; ++r) {
          float v = h3keep[j][r] + accA[j][r] + accB[j][r] * (1.f / 4096.f) + bs;
          h3keep[j][r] = v;
          short vh, vl;
          splitf16(fmaxf(v, 0.f), vh, vl);
          const int m = mt * 16 + quad * 4 + r;
          H2h[m * 72 + col] = vh;
          H2l[m * 72 + col] = vl;
        }
      }
    }
    __syncthreads();
  }

  { // ---- pre 1x1 -> z (fp32) + z planes (x256 scale for VQ) ----
    h8 wph[2], wpl[2];
#pragma unroll
    for (int ks = 0; ks < 2; ++ks) {
      const int wb = EPW_OFF + (nh * 16 + l15) * 64 + ks * 32 + quad * 8;
      wph[ks] = *reinterpret_cast<const h8*>(ewh + wb);
      wpl[ks] = *reinterpret_cast<const h8*>(ewl + wb);
    }
    const float bs = pb[nh * 16 + l15];
    f32x4 accA = zf4, accB = zf4;
    const int arow = mt * 16 + l15;
#pragma unroll
    for (int ks = 0; ks < 2; ++ks) {
      const int aoff = arow * 72 + ks * 32 + quad * 8;
      h8 ah = *reinterpret_cast<const h8*>(&H2h[aoff]);
      h8 al = *reinterpret_cast<const h8*>(&H2l[aoff]);
      accA = __builtin_amdgcn_mfma_f32_16x16x32_f16(ah, wph[ks], accA, 0, 0, 0);
      accB = __builtin_amdgcn_mfma_f32_16x16x32_f16(ah, wpl[ks], accB, 0, 0, 0);
      accB = __builtin_amdgcn_mfma_f32_16x16x32_f16(al, wph[ks], accB, 0, 0, 0);
    }
    const int pn = mt * 4 + quad;
    const int col = nh * 16 + l15;
    float ov[4];
#pragma unroll
    for (int r = 0; r < 4; ++r) ov[r] = accA[r] + accB[r] * (1.f / 4096.f) + bs;
    const size_t off = (pbase + pn) * 128 + col * 4;
    *reinterpret_cast<float4*>(z + off) = *reinterpret_cast<float4*>(ov);
    ushort4 h4, l4;
    unsigned short* hp = (unsigned short*)&h4;
    unsigned short* lp = (unsigned short*)&l4;
#pragma unroll
    for (int r = 0; r < 4; ++r) {
      short vh, vl;
      splitf16(ov[r] * 256.f, vh, vl);    // z*256: f16-normal
      hp[r] = (unsigned short)vh;
      lp[r] = (unsigned short)vl;
    }
    *reinterpret_cast<ushort4*>(&zh[off]) = h4;
    *reinterpret_cast<ushort4*>(&zl[off]) = l4;
  }
}

// ======= transformer weight cast: fp32 -> single bf16 plane (once/launch) =======
__global__ __launch_bounds__(256) void cast_w(
    const float* __restrict__ qkv_w, const float* __restrict__ proj_w,
    const float* __restrict__ f1, const float* __restrict__ f2,
    const float* __restrict__ hw, unsigned short* __restrict__ wb) {
  int i = blockIdx.x * 256 + threadIdx.x;
  float v;
  if (i < 196608) v = qkv_w[i];
  else if (i < 262144) v = proj_w[i - 196608];
  else if (i < 393216) v = f1[i - 262144];
  else if (i < 524288) v = f2[i - 393216];
  else v = hw[i - 524288];
  wb[i] = (unsigned short)f2bf(v);
}

// ====== VQ argmin v3: split-f16 MFMA GEMM z.cb^T + |c|^2 + fused argmin ======
// Planes carry z*256 and c*64 -> acc = 2^14 * z.c; s = acc/16384 (exact pow2).
__global__ __launch_bounds__(256) void vq_argmin3(
    const unsigned short* __restrict__ Ahg, const unsigned short* __restrict__ Alg,
    const unsigned short* __restrict__ Bhg, const unsigned short* __restrict__ Blg,
    const float* __restrict__ cbf, unsigned long long* __restrict__ keys) {
  __shared__ short Ah[128 * 40], Al[128 * 40], Bh[64 * 40], Bl[64 * 40];
  __shared__ float cns[64];
  const int tid = threadIdx.x;
  const int n0 = blockIdx.x * 64, m0 = blockIdx.y * 128;
  const int wave = tid >> 6, lane = tid & 63, quad = lane >> 4, l15 = lane & 15;
  const f32x4 z4 = {0.f, 0.f, 0.f, 0.f};
  f32x4 accA[2][4], accB[2][4];
#pragma unroll
  for (int i = 0; i < 2; ++i)
#pragma unroll
    for (int j = 0; j < 4; ++j) { accA[i][j] = z4; accB[i][j] = z4; }
  { // |c|^2 for the block's 64 cols (fp32)
    const int lr = tid >> 2, q = tid & 3;
    const float4* bp = reinterpret_cast<const float4*>(cbf + (size_t)(n0 + lr) * 128 + q * 32);
    float s = 0.f;
#pragma unroll
    for (int e = 0; e < 8; ++e) {
      float4 v = bp[e];
      s += v.x * v.x + v.y * v.y + v.z * v.z + v.w * v.w;
    }
    s += __shfl_xor(s, 1); s += __shfl_xor(s, 2);
    if (q == 0) cns[lr] = s;
  }
  const int ra = tid >> 1, ha = (tid & 1) * 16;         // A: 128 rows, 16 shorts each
  const int rb = tid >> 2, hb = (tid & 3) * 8;          // B: 64 rows, 8 shorts each
  for (int k0 = 0; k0 < 128; k0 += 32) {
    {
      const size_t abase = (size_t)(m0 + ra) * 128 + k0 + ha;
      *reinterpret_cast<bf8*>(&Ah[ra * 40 + ha])     = *reinterpret_cast<const bf8*>(&Ahg[abase]);
      *reinterpret_cast<bf8*>(&Ah[ra * 40 + ha + 8]) = *reinterpret_cast<const bf8*>(&Ahg[abase + 8]);
      *reinterpret_cast<bf8*>(&Al[ra * 40 + ha])     = *reinterpret_cast<const bf8*>(&Alg[abase]);
      *reinterpret_cast<bf8*>(&Al[ra * 40 + ha + 8]) = *reinterpret_cast<const bf8*>(&Alg[abase + 8]);
      const size_t bbase = (size_t)(n0 + rb) * 128 + k0 + hb;
      *reinterpret_cast<bf8*>(&Bh[rb * 40 + hb]) = *reinterpret_cast<const bf8*>(&Bhg[bbase]);
      *reinterpret_cast<bf8*>(&Bl[rb * 40 + hb]) = *reinterpret_cast<const bf8*>(&Blg[bbase]);
    }
    __syncthreads();
    h8 af[2], afl[2], bfh[4], bfl[4];
#pragma unroll
    for (int mt = 0; mt < 2; ++mt) {
      int row = wave * 32 + mt * 16 + l15;
      af[mt]  = *reinterpret_cast<const h8*>(&Ah[row * 40 + quad * 8]);
      afl[mt] = *reinterpret_cast<const h8*>(&Al[row * 40 + quad * 8]);
    }
#pragma unroll
    for (int nt = 0; nt < 4; ++nt) {
      int row = nt * 16 + l15;
      bfh[nt] = *reinterpret_cast<const h8*>(&Bh[row * 40 + quad * 8]);
      bfl[nt] = *reinterpret_cast<const h8*>(&Bl[row * 40 + quad * 8]);
    }
#pragma unroll
    for (int nt = 0; nt < 4; ++nt)
#pragma unroll
      for (int mt = 0; mt < 2; ++mt) {
        accA[mt][nt] = __builtin_amdgcn_mfma_f32_16x16x32_f16(af[mt], bfh[nt], accA[mt][nt], 0, 0, 0);
        accB[mt][nt] = __builtin_amdgcn_mfma_f32_16x16x32_f16(af[mt], bfl[nt], accB[mt][nt], 0, 0, 0);
        accB[mt][nt] = __builtin_amdgcn_mfma_f32_16x16x32_f16(afl[mt], bfh[nt], accB[mt][nt], 0, 0, 0);
      }
    __syncthreads();
  }
#pragma unroll
  for (int mt = 0; mt < 2; ++mt)
#pragma unroll
    for (int r = 0; r < 4; ++r) {
      const int row = m0 + wave * 32 + mt * 16 + quad * 4 + r;
      unsigned long long key = ~0ull;
#pragma unroll
      for (int nt = 0; nt < 4; ++nt) {
        const int c16 = nt * 16 + l15;
        float s = (accA[mt][nt][r] + accB[mt][nt][r] * (1.f / 4096.f)) * (1.f / 16384.f);
        float dv = cns[c16] - 2.f * s;            // |c|^2 - 2 z.c
        unsigned u = __float_as_uint(dv);
        u = (u & 0x80000000u) ? ~u : (u | 0x80000000u);  // order-preserving
        unsigned long long k = ((unsigned long long)u << 32) | (unsigned)(n0 + c16);
        key = k < key ? k : key;
      }
#pragma unroll
      for (int off = 1; off < 16; off <<= 1) {
        unsigned long long o = __shfl_xor(key, off);
        key = o < key ? o : key;
      }
      if (l15 == 0) atomicMin(&keys[row], key);
    }
}

// ===== VQ part 3: gather q, loss partials, hh = q + pos (fp32 + bf16 plane) =====
__global__ __launch_bounds__(256) void vq_gather3(
    const float* __restrict__ z, const float* __restrict__ cb,
    const float* __restrict__ pos, const unsigned long long* __restrict__ keys,
    float* __restrict__ hh, unsigned short* __restrict__ hh_b,
    float* __restrict__ lpart, float* __restrict__ idx_out) {
  const int blk = blockIdx.x, tid = threadIdx.x;
  __shared__ int sidx[8];
  if (tid < 8) {
    unsigned long long k = keys[blk * 8 + tid];
    int id = (int)(unsigned)(k & 0xffffffffull);
    sidx[tid] = id;
    idx_out[blk * 8 + tid] = (float)id;
  }
  __syncthreads();
  const int p = tid >> 5, d = tid & 31;
  const size_t n = (size_t)blk * 8 + p;
  const int idx = sidx[p];
  float4 q = *reinterpret_cast<const float4*>(cb + (size_t)idx * 128 + d * 4);
  float4 zv = *reinterpret_cast<const float4*>(z + n * 128 + d * 4);
  float4 pv = *reinterpret_cast<const float4*>(pos + (size_t)(n & 511) * 128 + d * 4);
  float hv[4] = {q.x + pv.x, q.y + pv.y, q.z + pv.z, q.w + pv.w};
  *reinterpret_cast<float4*>(hh + n * 128 + d * 4) = *reinterpret_cast<float4*>(hv);
  ushort4 h4;
  unsigned short* hp = (unsigned short*)&h4;
#pragma unroll
  for (int e = 0; e < 4; ++e) hp[e] = (unsigned short)f2bf(hv[e]);
  *reinterpret_cast<ushort4*>(&hh_b[n * 128 + d * 4]) = h4;
  float dx = q.x - zv.x, dy = q.y - zv.y, dz = q.z - zv.z, dw = q.w - zv.w;
  float part = dx * dx + dy * dy + dz * dz + dw * dw;
#pragma unroll
  for (int o = 1; o < 64; o <<= 1) part += __shfl_xor(part, o);
  __shared__ float lred[4];
  if ((tid & 63) == 0) lred[tid >> 6] = part;
  __syncthreads();
  if (tid == 0) lpart[blk] = lred[0] + lred[1] + lred[2] + lred[3];
}

// ====== plain-bf16 MFMA GEMM: C = A[M,128]*B[N,128]^T + bias ======
// tile 128(M) x 64(N).  ACT: 0=none 1=gelu.  SPLIT: 1 -> bf16 out, 0 -> fp32.
template <int ACT, int SPLIT>
__global__ __launch_bounds__(256) void mgemm_b(
    const unsigned short* __restrict__ Ag, const unsigned short* __restrict__ Bg,
    const float* __restrict__ bias, float* __restrict__ C,
    unsigned short* __restrict__ Cb, int N) {
  __shared__ short Ah[128 * 40], Bh[64 * 40];
  const int tid = threadIdx.x;
  const int n0 = blockIdx.x * 64, m0 = blockIdx.y * 128;
  const int wave = tid >> 6, lane = tid & 63, quad = lane >> 4, l15 = lane & 15;
  const f32x4 z4 = {0.f, 0.f, 0.f, 0.f};
  f32x4 acc[2][4];
#pragma unroll
  for (int i = 0; i < 2; ++i)
#pragma unroll
    for (int j = 0; j < 4; ++j) acc[i][j] = z4;

  const int ra = tid >> 1, ha = (tid & 1) * 16;         // A: 128 rows, 16 shorts each
  const int rb = tid >> 2, hb = (tid & 3) * 8;          // B: 64 rows, 8 shorts each
  for (int k0 = 0; k0 < 128; k0 += 32) {
    {
      const size_t abase = (size_t)(m0 + ra) * 128 + k0 + ha;
      *reinterpret_cast<bf8*>(&Ah[ra * 40 + ha])     = *reinterpret_cast<const bf8*>(&Ag[abase]);
      *reinterpret_cast<bf8*>(&Ah[ra * 40 + ha + 8]) = *reinterpret_cast<const bf8*>(&Ag[abase + 8]);
      const size_t bbase = (size_t)(n0 + rb) * 128 + k0 + hb;
      *reinterpret_cast<bf8*>(&Bh[rb * 40 + hb]) = *reinterpret_cast<const bf8*>(&Bg[bbase]);
    }
    __syncthreads();
    bf8 af[2], bfh[4];
#pragma unroll
    for (int mt = 0; mt < 2; ++mt)
      af[mt] = *reinterpret_cast<const bf8*>(&Ah[(wave * 32 + mt * 16 + l15) * 40 + quad * 8]);
#pragma unroll
    for (int nt = 0; nt < 4; ++nt)
      bfh[nt] = *reinterpret_cast<const bf8*>(&Bh[(nt * 16 + l15) * 40 + quad * 8]);
#pragma unroll
    for (int nt = 0; nt < 4; ++nt)
#pragma unroll
      for (int mt = 0; mt < 2; ++mt)
        acc[mt][nt] = __builtin_amdgcn_mfma_f32_16x16x32_bf16(af[mt], bfh[nt], acc[mt][nt], 0, 0, 0);
    __syncthreads();
  }
#pragma unroll
  for (int nt = 0; nt < 4; ++nt) {
    int col = n0 + nt * 16 + l15;
    float bv = bias[col];
#pragma unroll
    for (int mt = 0; mt < 2; ++mt) {
      int rbase = m0 + wave * 32 + mt * 16 + quad * 4;
#pragma unroll
      for (int r = 0; r < 4; ++r) {
        float v = acc[mt][nt][r] + bv;
        if (ACT == 1) v = 0.5f * v * (1.f + erff(v * 0.7071067811865476f));
        if (SPLIT) Cb[(size_t)(rbase + r) * N + col] = (unsigned short)f2bf(v);
        else       C[(size_t)(rbase + r) * N + col] = v;
      }
    }
  }
}

// == plain-bf16 MFMA GEMM + residual + LN (optionally + second/final LN) ==
// out = LN(A.B^T+bias+res)*g+b; FINAL=1: y = LN2(out)*g2+b2 -> bf16 only.
// tile 64(M) x 128(N).  K: 128 or 256.
template <int K, int FINAL>
__global__ __launch_bounds__(256) void mgemm_ln_b(
    const unsigned short* __restrict__ Ag, const unsigned short* __restrict__ Bg,
    const float* __restrict__ bias, const float* __restrict__ res,
    const float* __restrict__ g, const float* __restrict__ bb,
    const float* __restrict__ g2, const float* __restrict__ bb2,
    float* __restrict__ C, unsigned short* __restrict__ Cb) {
  __shared__ short Ah[64 * 40], Bh[128 * 40];
  const int tid = threadIdx.x;
  const int m0 = blockIdx.x * 64;
  const int wave = tid >> 6, lane = tid & 63, quad = lane >> 4, l15 = lane & 15;
  const f32x4 z4 = {0.f, 0.f, 0.f, 0.f};
  f32x4 acc[8];
#pragma unroll
  for (int j = 0; j < 8; ++j) acc[j] = z4;

  const int ra = tid >> 2, ha = (tid & 3) * 8;          // A: 64 rows, 8 shorts each
  const int rb = tid >> 1, hb = (tid & 1) * 16;         // B: 128 rows, 16 shorts each
  for (int k0 = 0; k0 < K; k0 += 32) {
    {
      const size_t abase = (size_t)(m0 + ra) * K + k0 + ha;
      *reinterpret_cast<bf8*>(&Ah[ra * 40 + ha]) = *reinterpret_cast<const bf8*>(&Ag[abase]);
      const size_t bbase = (size_t)rb * K + k0 + hb;
      *reinterpret_cast<bf8*>(&Bh[rb * 40 + hb])     = *reinterpret_cast<const bf8*>(&Bg[bbase]);
      *reinterpret_cast<bf8*>(&Bh[rb * 40 + hb + 8]) = *reinterpret_cast<const bf8*>(&Bg[bbase + 8]);
    }
    __syncthreads();
    bf8 af = *reinterpret_cast<const bf8*>(&Ah[(wave * 16 + l15) * 40 + quad * 8]);
    bf8 bfh[8];
#pragma unroll
    for (int nt = 0; nt < 8; ++nt)
      bfh[nt] = *reinterpret_cast<const bf8*>(&Bh[(nt * 16 + l15) * 40 + quad * 8]);
#pragma unroll
    for (int nt = 0; nt < 8; ++nt)
      acc[nt] = __builtin_amdgcn_mfma_f32_16x16x32_bf16(af, bfh[nt], acc[nt], 0, 0, 0);
    __syncthreads();
  }
  float bias_v[8], g_v[8], bb_v[8], g2_v[8], bb2_v[8];
#pragma unroll
  for (int nt = 0; nt < 8; ++nt) {
    int col = nt * 16 + l15;
    bias_v[nt] = bias[col]; g_v[nt] = g[col]; bb_v[nt] = bb[col];
    if (FINAL) { g2_v[nt] = g2[col]; bb2_v[nt] = bb2[col]; }
  }
  const int rbase = m0 + wave * 16 + quad * 4;
#pragma unroll
  for (int r = 0; r < 4; ++r) {
    const int row = rbase + r;
    float ov[8];
    float s = 0.f;
#pragma unroll
    for (int nt = 0; nt < 8; ++nt) {
      ov[nt] = acc[nt][r] + bias_v[nt] + res[(size_t)row * 128 + nt * 16 + l15];
      s += ov[nt];
    }
    s += __shfl_xor(s, 1); s += __shfl_xor(s, 2);
    s += __shfl_xor(s, 4); s += __shfl_xor(s, 8);
    float mean = s * 0.0078125f;
    float s2 = 0.f;
#pragma unroll
    for (int nt = 0; nt < 8; ++nt) { ov[nt] -= mean; s2 += ov[nt] * ov[nt]; }
    s2 += __shfl_xor(s2, 1); s2 += __shfl_xor(s2, 2);
    s2 += __shfl_xor(s2, 4); s2 += __shfl_xor(s2, 8);
    float rstd = rsqrtf(s2 * 0.0078125f + 1e-5f);
    if (FINAL) {
      float yv[8];
      float s3 = 0.f;
#pragma unroll
      for (int nt = 0; nt < 8; ++nt) { yv[nt] = ov[nt] * rstd * g_v[nt] + bb_v[nt]; s3 += yv[nt]; }
      s3 += __shfl_xor(s3, 1); s3 += __shfl_xor(s3, 2);
      s3 += __shfl_xor(s3, 4); s3 += __shfl_xor(s3, 8);
      float mean2 = s3 * 0.0078125f;
      float s4 = 0.f;
#pragma unroll
      for (int nt = 0; nt < 8; ++nt) { yv[nt] -= mean2; s4 += yv[nt] * yv[nt]; }
      s4 += __shfl_xor(s4, 1); s4 += __shfl_xor(s4, 2);
      s4 += __shfl_xor(s4, 4); s4 += __shfl_xor(s4, 8);
      float rstd2 = rsqrtf(s4 * 0.0078125f + 1e-5f);
#pragma unroll
      for (int nt = 0; nt < 8; ++nt) {
        float v = yv[nt] * rstd2 * g2_v[nt] + bb2_v[nt];
        Cb[(size_t)row * 128 + nt * 16 + l15] = (unsigned short)f2bf(v);
      }
    } else {
#pragma unroll
      for (int nt = 0; nt < 8; ++nt) {
        float v = ov[nt] * rstd * g_v[nt] + bb_v[nt];
        size_t off = (size_t)row * 128 + nt * 16 + l15;
        C[off] = v;
        Cb[off] = (unsigned short)f2bf(v);
      }
    }
  }
}

// ====== plain-bf16 MFMA flash attention: block per (qt,h,b) ======
__global__ __launch_bounds__(256) void attn_b(
    const unsigned short* __restrict__ qb, unsigned short* __restrict__ ob) {
  const int qt = blockIdx.x, h = blockIdx.y, b = blockIdx.z;
  __shared__ short Kh[64 * 40];          // [key][d]
  __shared__ short Vth[32 * 72];         // [d][key]
  __shared__ float Ss[64 * 72];
  __shared__ float ms[64], ls[64], alphas[64];
  const int tid = threadIdx.x;
  const int wave = tid >> 6, lane = tid & 63, quad = lane >> 4, l15 = lane & 15;
  const size_t tbase = (size_t)b * 512 + qt * 64;
  bf8 qf;
  {
    const size_t qoff = (tbase + wave * 16 + l15) * 384 + h * 32 + quad * 8;
    qf = *reinterpret_cast<const bf8*>(&qb[qoff]);
  }
  if (tid < 64) { ms[tid] = -1e30f; ls[tid] = 0.f; }
  const f32x4 z4 = {0.f, 0.f, 0.f, 0.f};
  f32x4 o[2] = {z4, z4};
  const float scale = 0.17677669529663687f;  // 1/sqrt(32)
  const int sr = tid >> 2, sc8 = (tid & 3) * 8;
  for (int kt = 0; kt <= qt; ++kt) {
    const size_t kbase = (size_t)b * 512 + kt * 64;
    {
      const size_t koff = (kbase + sr) * 384 + 128 + h * 32 + sc8;
      *reinterpret_cast<bf8*>(&Kh[sr * 40 + sc8]) = *reinterpret_cast<const bf8*>(&qb[koff]);
      const size_t voff = (kbase + sr) * 384 + 256 + h * 32 + sc8;
      bf8 vh8 = *reinterpret_cast<const bf8*>(&qb[voff]);
#pragma unroll
      for (int j = 0; j < 8; ++j) Vth[(sc8 + j) * 72 + sr] = vh8[j];
    }
    __syncthreads();
    {
#pragma unroll
      for (int nt = 0; nt < 4; ++nt) {
        bf8 kf = *reinterpret_cast<const bf8*>(&Kh[(nt * 16 + l15) * 40 + quad * 8]);
        f32x4 s = __builtin_amdgcn_mfma_f32_16x16x32_bf16(qf, kf, z4, 0, 0, 0);
#pragma unroll
        for (int r = 0; r < 4; ++r) {
          int row64 = wave * 16 + quad * 4 + r;
          int col64 = nt * 16 + l15;
          float v = s[r] * scale;
          if (kt == qt && col64 > row64) v += -1e9f;
          Ss[row64 * 72 + col64] = v;
        }
      }
    }
    __syncthreads();
    {
      const int i = tid >> 2, q = tid & 3;
      float mx = -3.4e38f;
      float4 pv[4];
#pragma unroll
      for (int t = 0; t < 4; ++t) {
        pv[t] = *reinterpret_cast<const float4*>(&Ss[i * 72 + q * 16 + t * 4]);
        mx = fmaxf(mx, fmaxf(fmaxf(pv[t].x, pv[t].y), fmaxf(pv[t].z, pv[t].w)));
      }
      mx = fmaxf(mx, __shfl_xor(mx, 1));
      mx = fmaxf(mx, __shfl_xor(mx, 2));
      float mold = ms[i];
      mx = fmaxf(mx, mold);
      float sum = 0.f;
#pragma unroll
      for (int t = 0; t < 4; ++t) {
        pv[t].x = __expf(pv[t].x - mx); pv[t].y = __expf(pv[t].y - mx);
        pv[t].z = __expf(pv[t].z - mx); pv[t].w = __expf(pv[t].w - mx);
        sum += pv[t].x + pv[t].y + pv[t].z + pv[t].w;
        *reinterpret_cast<float4*>(&Ss[i * 72 + q * 16 + t * 4]) = pv[t];
      }
      sum += __shfl_xor(sum, 1);
      sum += __shfl_xor(sum, 2);
      if (q == 0) {
        float alpha = __expf(mold - mx);
        ls[i] = ls[i] * alpha + sum;
        ms[i] = mx;
        alphas[i] = alpha;
      }
    }
    __syncthreads();
    {
      bf8 ph[2];
#pragma unroll
      for (int c = 0; c < 2; ++c) {
        const float* pp = &Ss[(wave * 16 + l15) * 72 + c * 32 + quad * 8];
        float4 p0 = *reinterpret_cast<const float4*>(pp);
        float4 p1 = *reinterpret_cast<const float4*>(pp + 4);
        float pf[8] = {p0.x, p0.y, p0.z, p0.w, p1.x, p1.y, p1.z, p1.w};
#pragma unroll
        for (int j = 0; j < 8; ++j) ph[c][j] = f2bf(pf[j]);
      }
      float a0 = alphas[wave * 16 + quad * 4 + 0];
      float a1 = alphas[wave * 16 + quad * 4 + 1];
      float a2 = alphas[wave * 16 + quad * 4 + 2];
      float a3 = alphas[wave * 16 + quad * 4 + 3];
#pragma unroll
      for (int dt = 0; dt < 2; ++dt) {
        o[dt][0] *= a0; o[dt][1] *= a1; o[dt][2] *= a2; o[dt][3] *= a3;
#pragma unroll
        for (int c = 0; c < 2; ++c) {
          bf8 vf = *reinterpret_cast<const bf8*>(&Vth[(dt * 16 + l15) * 72 + c * 32 + quad * 8]);
          o[dt] = __builtin_amdgcn_mfma_f32_16x16x32_bf16(ph[c], vf, o[dt], 0, 0, 0);
        }
      }
    }
    __syncthreads();
  }
#pragma unroll
  for (int r = 0; r < 4; ++r) {
    float inv = 1.f / ls[wave * 16 + quad * 4 + r];
    size_t row = tbase + wave * 16 + quad * 4 + r;
#pragma unroll
    for (int dt = 0; dt < 2; ++dt) {
      float v = o[dt][r] * inv;
      ob[row * 128 + h * 32 + dt * 16 + l15] = (unsigned short)f2bf(v);
    }
  }
}

__global__ __launch_bounds__(256) void loss_finalize2(const float* __restrict__ lp,
                                                      float* __restrict__ out) {
  float s = 0.f;
  for (int i = threadIdx.x; i < 2048; i += 256) s += lp[i];
#pragma unroll
  for (int o = 1; o < 64; o <<= 1) s += __shfl_xor(s, o);
  __shared__ float red[4];
  if ((threadIdx.x & 63) == 0) red[threadIdx.x >> 6] = s;
  __syncthreads();
  if (threadIdx.x == 0)
    out[0] = 1.25f * (red[0] + red[1] + red[2] + red[3]) / 2097152.0f;
}

extern "C" void kernel_launch(void* const* d_in, const int* in_sizes, int n_in,
                              void* d_out, int out_size, void* d_ws, size_t ws_size,
                              hipStream_t stream) {
  const float* x      = (const float*)d_in[0];
  const float* enc_w1 = (const float*)d_in[1];
  const float* enc_b1 = (const float*)d_in[2];
  const float* enc_w2 = (const float*)d_in[3];
  const float* enc_b2 = (const float*)d_in[4];
  const float* enc_w3 = (const float*)d_in[5];
  const float* enc_b3 = (const float*)d_in[6];
  const float* res_w1 = (const float*)d_in[7];
  const float* res_b1 = (const float*)d_in[8];
  const float* res_w2 = (const float*)d_in[9];
  const float* res_b2 = (const float*)d_in[10];
  const float* pre_w  = (const float*)d_in[11];
  const float* pre_b  = (const float*)d_in[12];
  const float* codebook = (const float*)d_in[13];
  const float* pos_emb  = (const float*)d_in[14];
  const float* qkv_w  = (const float*)d_in[15];
  const float* qkv_b  = (const float*)d_in[16];
  const float* proj_w = (const float*)d_in[17];
  const float* proj_b = (const float*)d_in[18];
  const float* ln1_g  = (const float*)d_in[19];
  const float* ln1_b  = (const float*)d_in[20];
  const float* ln2_g  = (const float*)d_in[21];
  const float* ln2_b  = (const float*)d_in[22];
  const float* ffn_w1 = (const float*)d_in[23];
  const float* ffn_b1 = (const float*)d_in[24];
  const float* ffn_w2 = (const float*)d_in[25];
  const float* ffn_b2 = (const float*)d_in[26];
  const float* fin_g  = (const float*)d_in[27];
  const float* fin_b  = (const float*)d_in[28];
  const float* head_w = (const float*)d_in[29];
  const float* head_b = (const float*)d_in[30];

  float* out = (float*)d_out;
  float* ws  = (float*)d_ws;

  // ws: keys(32768f) | lpart(2048) | pad | wb plane | hhln_b plane
  unsigned long long* keys = (unsigned long long*)ws;
  float* lpart = ws + 32768;
  unsigned short* wb = (unsigned short*)(ws + 36864);        // 589824 ushorts
  unsigned short* hhln_b = (unsigned short*)(ws + 692224);   // 2097152 ushorts

  // d_out scratch overlay (float offsets; dead before head GEMM)
  float* zf = out;                                            // [0 .. 2^21)
  float* hh = out + 2097152;                                  // [2^21 .. 2^22)
  unsigned short* hh_b   = (unsigned short*)(out + 4194304);  // 2M ushorts
  unsigned short* qkvb_b = (unsigned short*)(out + 6291456);  // 6.29M ushorts
  unsigned short* oatt_b = (unsigned short*)(out + 12582912); // 2M ushorts
  unsigned short* fbuf_b = (unsigned short*)(out + 0);        // overlays zf (dead)

  // encoder weight planes overlay qkvb region (dead until first mgemm_b)
  unsigned short* ewh = (unsigned short*)(out + 6291456);
  unsigned short* ewl = ewh + EWTOT;                          // ends < out+6330368

  // z planes (dead after vq_argmin3, before qkv writes qkvb region)
  unsigned short* zh = (unsigned short*)(out + 6340608);
  unsigned short* zl = (unsigned short*)(out + 7389184);
  // codebook planes + |c|^2 (overlay oatt region, dead until attn_b)
  unsigned short* cbh = (unsigned short*)(out + 12582912);
  unsigned short* cbl = (unsigned short*)(out + 12648448);
  float* cnbuf = out + 12713984;

  const int W_QKV = 0, W_PROJ = 196608, W_F1 = 262144, W_F2 = 393216, W_HEAD = 524288;

  hipMemsetAsync(keys, 0xFF, NPATCH * sizeof(unsigned long long), stream);

  enc_split<<<152, 256, 0, stream>>>(enc_w2, enc_w3, res_w1, res_w2, pre_w, ewh, ewl);
  cb_split<<<512, 256, 0, stream>>>(codebook, cbh, cbl, cnbuf);
  encoder7<<<2048, 256, 0, stream>>>(x, enc_w1, enc_b1, enc_b2, enc_b3,
                                     res_b1, res_b2, pre_b, ewh, ewl, zf, zh, zl);
  cast_w<<<2304, 256, 0, stream>>>(qkv_w, proj_w, ffn_w1, ffn_w2, head_w, wb);
  vq_argmin3<<<dim3(16, 128), 256, 0, stream>>>(zh, zl, cbh, cbl, codebook, keys);
  vq_gather3<<<2048, 256, 0, stream>>>(zf, codebook, pos_emb, keys, hh, hh_b,
                                       lpart, out + IDX_OFF);
  for (int i = 0; i < 4; ++i) {
    mgemm_b<0, 1><<<dim3(6, 128), 256, 0, stream>>>(
        hh_b, wb + W_QKV + i * 49152, qkv_b + i * 384, nullptr, qkvb_b, 384);
    attn_b<<<dim3(8, 4, 32), 256, 0, stream>>>(qkvb_b, oatt_b);
    mgemm_ln_b<128, 0><<<256, 256, 0, stream>>>(
        oatt_b, wb + W_PROJ + i * 16384, proj_b + i * 128, hh,
        ln1_g + i * 128, ln1_b + i * 128, nullptr, nullptr, hh, hh_b);
    mgemm_b<1, 1><<<dim3(4, 128), 256, 0, stream>>>(
        hh_b, wb + W_F1 + i * 32768, ffn_b1 + i * 256, nullptr, fbuf_b, 256);
    if (i < 3) {
      mgemm_ln_b<256, 0><<<256, 256, 0, stream>>>(
          fbuf_b, wb + W_F2 + i * 32768, ffn_b2 + i * 128, hh,
          ln2_g + i * 128, ln2_b + i * 128, nullptr, nullptr, hh, hh_b);
    } else {
      mgemm_ln_b<256, 1><<<256, 256, 0, stream>>>(
          fbuf_b, wb + W_F2 + i * 32768, ffn_b2 + i * 128, hh,
          ln2_g + i * 128, ln2_b + i * 128, fin_g, fin_b, hh, hhln_b);
    }
  }
  mgemm_b<0, 0><<<dim3(16, 128), 256, 0, stream>>>(
      hhln_b, wb + W_HEAD, head_b, out, nullptr, 1024);
  loss_finalize2<<<1, 256, 0, stream>>>(lpart, out + LOSS_OFF);
}